// Round 7
// baseline (1571.339 us; speedup 1.0000x reference)
//
#include <hip/hip_runtime.h>
#include <math.h>

#define D 64
#define NBB 128    // blocks doing the bin pass (rest of grid runs mm1)
#define NPB 128    // nodes per bin (dst >> 7); 782 bins for N=100K
#define NBINMAX 2048

__device__ __forceinline__ float lrelu(float x, float s) { return x > 0.f ? x : s * x; }

// f32 -> bf16 round-to-nearest-even
__device__ __forceinline__ unsigned f2bf(float f) {
    unsigned b = __builtin_bit_cast(unsigned, f);
    return (b + 0x7fffu + ((b >> 16) & 1u)) >> 16;
}
__device__ __forceinline__ float bflo(unsigned u) { return __builtin_bit_cast(float, u << 16); }
__device__ __forceinline__ float bfhi(unsigned u) { return __builtin_bit_cast(float, u & 0xffff0000u); }

// mm body (round-3 form: W column cached in registers).
__device__ __forceinline__ void mm_rows(const float* __restrict__ xin,
        const float* __restrict__ W, const float* __restrict__ a_src, const float* __restrict__ a_dst,
        const float* __restrict__ bn_sum, const float* __restrict__ bn_sumsq,
        const float* __restrict__ gamma, const float* __restrict__ beta, int apply_bn,
        unsigned* __restrict__ hb, float* __restrict__ ssrc, float* __restrict__ sdst,
        int N, int worker, int nworkers, int lane, int wv) {
    float w[D];
    #pragma unroll
    for (int k = 0; k < D; ++k) w[k] = W[k * D + lane];   // column `lane`
    float asv = a_src[lane], adv = a_dst[lane];
    float sc = 1.f, sh = 0.f;
    if (apply_bn) {
        float mu = bn_sum[lane] / (float)N;
        float var = bn_sumsq[lane] / (float)N - mu * mu;   // biased var = jnp.var
        float rs = rsqrtf(var + 1e-5f);
        sc = rs * gamma[lane];
        sh = beta[lane] - mu * sc;
    }
    for (int r = worker * 4 + wv; r < N; r += nworkers * 4) {
        float v = xin[(size_t)r * D + lane];
        if (apply_bn) { v = v * sc + sh; v = v > 0.f ? v : 0.01f * v; }
        int vi = __builtin_bit_cast(int, v);
        float a0 = 0.f, a1 = 0.f, a2 = 0.f, a3 = 0.f;   // 4 chains break FMA latency
        #pragma unroll
        for (int k = 0; k < D; k += 4) {
            float b0 = __builtin_bit_cast(float, __builtin_amdgcn_readlane(vi, k + 0));
            float b1 = __builtin_bit_cast(float, __builtin_amdgcn_readlane(vi, k + 1));
            float b2 = __builtin_bit_cast(float, __builtin_amdgcn_readlane(vi, k + 2));
            float b3 = __builtin_bit_cast(float, __builtin_amdgcn_readlane(vi, k + 3));
            a0 = fmaf(b0, w[k + 0], a0);
            a1 = fmaf(b1, w[k + 1], a1);
            a2 = fmaf(b2, w[k + 2], a2);
            a3 = fmaf(b3, w[k + 3], a3);
        }
        float acc = (a0 + a1) + (a2 + a3);
        // pack col pairs to bf16x2; even lanes store 4B (row = 32 uints = 128B)
        float accp = __shfl_xor(acc, 1, 64);
        unsigned packed = f2bf(acc) | (f2bf(accp) << 16);
        if (!(lane & 1)) hb[(size_t)r * 32 + (lane >> 1)] = packed;
        float v1 = acc * asv, v2 = acc * adv;
        #pragma unroll
        for (int off = 32; off; off >>= 1) {
            v1 += __shfl_xor(v1, off, 64);
            v2 += __shfl_xor(v2, off, 64);
        }
        if (lane == 0) { ssrc[r] = v1; sdst[r] = v2; }
    }
}

// Pass 1 fused with layer-1 mm.
// Blocks [0,NBB): bin edges by dst>>7 into per-bin contiguous regions of `binned`.
// Blocks [NBB, grid): layer-1 mm.
__global__ __launch_bounds__(256) void k_bin_mm1(const int* __restrict__ ei, int E,
        int* __restrict__ bin_ptr, int2* __restrict__ binned, int BCAP,
        const float* __restrict__ xin, const float* __restrict__ W,
        const float* __restrict__ a_src, const float* __restrict__ a_dst,
        unsigned* __restrict__ hb, float* __restrict__ ssrc, float* __restrict__ sdst, int N) {
    __shared__ int hist[NBINMAX], cur[NBINMAX];
    int tid = threadIdx.x, lane = tid & 63, wv = tid >> 6;
    if (blockIdx.x < NBB) {
        int nb = (N + NPB - 1) >> 7;
        for (int t = tid; t < nb; t += 256) hist[t] = 0;
        __syncthreads();
        int nq4 = E >> 2;
        int qpb = (nq4 + NBB - 1) / NBB;
        int q0 = blockIdx.x * qpb;
        int q1 = q0 + qpb; if (q1 > nq4) q1 = nq4;
        const int4* s4 = (const int4*)ei;
        const int4* d4 = (const int4*)(ei + E);
        // pass A: LDS histogram over bins
        for (int i = q0 + tid; i < q1; i += 256) {
            int4 d = d4[i];
            atomicAdd(&hist[d.x >> 7], 1);
            atomicAdd(&hist[d.y >> 7], 1);
            atomicAdd(&hist[d.z >> 7], 1);
            atomicAdd(&hist[d.w >> 7], 1);
        }
        if (blockIdx.x == 0 && tid < (E & 3)) {
            int dd = ei[E + (nq4 << 2) + tid];
            atomicAdd(&hist[dd >> 7], 1);
        }
        __syncthreads();
        // reserve contiguous slices per bin (device atomics: one per (block,bin))
        for (int t = tid; t < nb; t += 256)
            cur[t] = hist[t] ? atomicAdd(&bin_ptr[t], hist[t]) : 0;
        __syncthreads();
        // pass B: place edges (dst re-read is L2-hot)
        for (int i = q0 + tid; i < q1; i += 256) {
            int4 s = s4[i];
            int4 d = d4[i];
            int t0 = d.x >> 7, t1 = d.y >> 7, t2 = d.z >> 7, t3 = d.w >> 7;
            int p0 = atomicAdd(&cur[t0], 1);
            int p1 = atomicAdd(&cur[t1], 1);
            int p2 = atomicAdd(&cur[t2], 1);
            int p3 = atomicAdd(&cur[t3], 1);
            if (p0 < BCAP) binned[(size_t)t0 * BCAP + p0] = make_int2(s.x, d.x);
            if (p1 < BCAP) binned[(size_t)t1 * BCAP + p1] = make_int2(s.y, d.y);
            if (p2 < BCAP) binned[(size_t)t2 * BCAP + p2] = make_int2(s.z, d.z);
            if (p3 < BCAP) binned[(size_t)t3 * BCAP + p3] = make_int2(s.w, d.w);
        }
        if (blockIdx.x == 0 && tid < (E & 3)) {
            int i = (nq4 << 2) + tid;
            int ss = ei[i], dd = ei[E + i];
            int t = dd >> 7;
            int p = atomicAdd(&cur[t], 1);
            if (p < BCAP) binned[(size_t)t * BCAP + p] = make_int2(ss, dd);
        }
    } else {
        mm_rows(xin, W, a_src, a_dst, nullptr, nullptr, nullptr, nullptr, 0,
                hb, ssrc, sdst, N, blockIdx.x - NBB, gridDim.x - NBB, lane, wv);
    }
}

// standalone layer-2 mm (BN folded in)
__global__ __launch_bounds__(256) void k_mm_att(const float* __restrict__ xin,
        const float* __restrict__ W, const float* __restrict__ a_src, const float* __restrict__ a_dst,
        const float* __restrict__ bn_sum, const float* __restrict__ bn_sumsq,
        const float* __restrict__ gamma, const float* __restrict__ beta,
        unsigned* __restrict__ hb, float* __restrict__ ssrc, float* __restrict__ sdst, int N) {
    int tid = threadIdx.x, lane = tid & 63, wv = tid >> 6;
    mm_rows(xin, W, a_src, a_dst, bn_sum, bn_sumsq, gamma, beta, 1,
            hb, ssrc, sdst, N, blockIdx.x, gridDim.x, lane, wv);
}

// EDGE-PARALLEL aggregation: one block per 128-dst-node bin. Edges streamed
// flat from `binned` (coalesced addresses -> NO dependent-address chains, the
// round-6 latency limiter); weighted h-rows LDS-fadd'ed into a 128x64 fp32
// tile; z is just another LDS accumulator (the per-node cross-lane z-reduce
// is gone). Single pass: acc=SUM e*h, z=SUM e; epilogue adds self-loop,
// divides, applies bias (+BN stats / final mix). 16-lane group per edge;
// x4 unrolled -> 4 independent 128B gathers/group, 64/wave in flight.
// acc rows padded to 68 floats to spread concurrent groups across banks.
// mode 0: out = agg/z + bias (fp32), accumulate BN col sums.
// mode 1: out = 0.5*(x + agg/z + bias)
__global__ __launch_bounds__(256) void k_agg(const int2* __restrict__ binned,
        const int* __restrict__ bin_ptr, int BCAP,
        const float* __restrict__ ssrc, const float* __restrict__ sdst,
        const unsigned* __restrict__ hb, const float* __restrict__ bias,
        const float* __restrict__ x, float* __restrict__ out,
        float* __restrict__ bn_sum, float* __restrict__ bn_sumsq, int mode, int N) {
    __shared__ float accs[NPB][68];    // 34.8KB, padded stride
    __shared__ float zz[NPB];
    __shared__ float sds[NPB];
    __shared__ float sbn1[D], sbn2[D];
    int tid = threadIdx.x;
    int sl = tid & 15;                 // lane in group: cols 4sl..4sl+3
    int g = tid >> 4;                  // group 0..15
    int b = blockIdx.x;
    int n0 = b << 7;

    for (int i = tid; i < NPB * 68; i += 256) ((float*)accs)[i] = 0.f;
    if (tid < NPB) {
        zz[tid] = 0.f;
        int nd = n0 + tid;
        sds[tid] = (nd < N) ? sdst[nd] : 0.f;
    }
    if (mode == 0 && tid < D) { sbn1[tid] = 0.f; sbn2[tid] = 0.f; }
    __syncthreads();

    int m = bin_ptr[b]; if (m > BCAP) m = BCAP;
    const int2* base = binned + (size_t)b * BCAP;
    const uint2* h2 = (const uint2*)hb;           // row = 16 uint2

    for (int i = g; i < m; i += 64) {
        int i1 = i + 16, i2 = i + 32, i3 = i + 48;
        bool v1 = i1 < m, v2 = i2 < m, v3 = i3 < m;
        int2 E0 = base[i];
        int2 E1 = base[v1 ? i1 : i];
        int2 E2 = base[v2 ? i2 : i];
        int2 E3 = base[v3 ? i3 : i];
        // independent gathers: 4 ssrc (broadcast) + 4 h-rows in flight
        float q0 = ssrc[E0.x], q1 = ssrc[E1.x], q2 = ssrc[E2.x], q3 = ssrc[E3.x];
        uint2 h0 = h2[(size_t)E0.x * 16 + sl];
        uint2 h1 = h2[(size_t)E1.x * 16 + sl];
        uint2 hh2 = h2[(size_t)E2.x * 16 + sl];
        uint2 h3 = h2[(size_t)E3.x * 16 + sl];
        int d0 = E0.y & 127, d1 = E1.y & 127, d2 = E2.y & 127, d3 = E3.y & 127;
        float e0 = __expf(lrelu(q0 + sds[d0], 0.2f));
        float e1 = __expf(lrelu(q1 + sds[d1], 0.2f));
        float e2 = __expf(lrelu(q2 + sds[d2], 0.2f));
        float e3 = __expf(lrelu(q3 + sds[d3], 0.2f));
        int c = sl << 2;
        {
            if (sl == 0) atomicAdd(&zz[d0], e0);
            float* ar = accs[d0];
            atomicAdd(&ar[c + 0], e0 * bflo(h0.x));
            atomicAdd(&ar[c + 1], e0 * bfhi(h0.x));
            atomicAdd(&ar[c + 2], e0 * bflo(h0.y));
            atomicAdd(&ar[c + 3], e0 * bfhi(h0.y));
        }
        if (v1) {
            if (sl == 0) atomicAdd(&zz[d1], e1);
            float* ar = accs[d1];
            atomicAdd(&ar[c + 0], e1 * bflo(h1.x));
            atomicAdd(&ar[c + 1], e1 * bfhi(h1.x));
            atomicAdd(&ar[c + 2], e1 * bflo(h1.y));
            atomicAdd(&ar[c + 3], e1 * bfhi(h1.y));
        }
        if (v2) {
            if (sl == 0) atomicAdd(&zz[d2], e2);
            float* ar = accs[d2];
            atomicAdd(&ar[c + 0], e2 * bflo(hh2.x));
            atomicAdd(&ar[c + 1], e2 * bfhi(hh2.x));
            atomicAdd(&ar[c + 2], e2 * bflo(hh2.y));
            atomicAdd(&ar[c + 3], e2 * bfhi(hh2.y));
        }
        if (v3) {
            if (sl == 0) atomicAdd(&zz[d3], e3);
            float* ar = accs[d3];
            atomicAdd(&ar[c + 0], e3 * bflo(h3.x));
            atomicAdd(&ar[c + 1], e3 * bfhi(h3.x));
            atomicAdd(&ar[c + 2], e3 * bflo(h3.y));
            atomicAdd(&ar[c + 3], e3 * bfhi(h3.y));
        }
    }
    __syncthreads();

    // epilogue: each group handles nodes g, g+16, ..., g+112
    float4 s1 = make_float4(0, 0, 0, 0), s2 = make_float4(0, 0, 0, 0);
    int c = sl << 2;
    for (int ii = g; ii < NPB; ii += 16) {
        int nd = n0 + ii;
        if (nd < N) {
            float ssn = ssrc[nd];
            float es = __expf(lrelu(ssn + sds[ii], 0.2f));
            float zt = zz[ii] + es;
            uint2 hv = h2[(size_t)nd * 16 + sl];   // self-loop row (coalesced)
            float inv = 1.f / zt;
            float4 b4 = ((const float4*)bias)[sl];
            float4 v;
            v.x = fmaf(es, bflo(hv.x), accs[ii][c + 0]) * inv + b4.x;
            v.y = fmaf(es, bfhi(hv.x), accs[ii][c + 1]) * inv + b4.y;
            v.z = fmaf(es, bflo(hv.y), accs[ii][c + 2]) * inv + b4.z;
            v.w = fmaf(es, bfhi(hv.y), accs[ii][c + 3]) * inv + b4.w;
            if (mode == 0) {
                ((float4*)out)[(size_t)nd * 16 + sl] = v;
                s1.x += v.x; s1.y += v.y; s1.z += v.z; s1.w += v.w;
                s2.x += v.x * v.x; s2.y += v.y * v.y;
                s2.z += v.z * v.z; s2.w += v.w * v.w;
            } else {
                float4 xv = ((const float4*)x)[(size_t)nd * 16 + sl];
                v.x = 0.5f * (xv.x + v.x); v.y = 0.5f * (xv.y + v.y);
                v.z = 0.5f * (xv.z + v.z); v.w = 0.5f * (xv.w + v.w);
                ((float4*)out)[(size_t)nd * 16 + sl] = v;
            }
        }
    }
    if (mode == 0) {
        atomicAdd(&sbn1[c + 0], s1.x); atomicAdd(&sbn1[c + 1], s1.y);
        atomicAdd(&sbn1[c + 2], s1.z); atomicAdd(&sbn1[c + 3], s1.w);
        atomicAdd(&sbn2[c + 0], s2.x); atomicAdd(&sbn2[c + 1], s2.y);
        atomicAdd(&sbn2[c + 2], s2.z); atomicAdd(&sbn2[c + 3], s2.w);
        __syncthreads();
        if (tid < D) {
            atomicAdd(&bn_sum[tid], sbn1[tid]);
            atomicAdd(&bn_sumsq[tid], sbn2[tid]);
        }
    }
}

extern "C" void kernel_launch(void* const* d_in, const int* in_sizes, int n_in,
                              void* d_out, int out_size, void* d_ws, size_t ws_size,
                              hipStream_t stream) {
    const float* x     = (const float*)d_in[0];
    const float* W1    = (const float*)d_in[1];
    const float* as1   = (const float*)d_in[2];
    const float* ad1   = (const float*)d_in[3];
    const float* b1    = (const float*)d_in[4];
    const float* gamma = (const float*)d_in[5];
    const float* beta  = (const float*)d_in[6];
    const float* W2    = (const float*)d_in[7];
    const float* as2   = (const float*)d_in[8];
    const float* ad2   = (const float*)d_in[9];
    const float* b2    = (const float*)d_in[10];
    const int*   ei    = (const int*)d_in[11];
    int N = in_sizes[0] / D;
    int E = in_sizes[11] / 2;
    float* out = (float*)d_out;          // layer-1 output buffer (fp32), then final

    float* ws = (float*)d_ws;
    unsigned* hb = (unsigned*)ws;                 // bf16-packed h: N*32 uints (12.8MB)
    float* ssrc = (float*)(hb + (size_t)N * 32);
    float* sdst = ssrc + N;
    int* binp   = (int*)(sdst + N);               // NBINMAX bin totals (memset)
    float* bn   = (float*)(binp + NBINMAX);       // 128: sum(64) | sumsq(64) (memset, contiguous)
    int2* binned = (int2*)(bn + 128);             // nb*BCAP edges (~18MB, lives in ws now)

    int nb = (N + NPB - 1) >> 7;                  // 782 bins for N=100K
    int BCAP = E / nb + (E / nb) / 4 + 256;       // avg + 25% + slack

    dim3 blk(256);

    // zero bin totals + bn in one async memset
    hipMemsetAsync(binp, 0, NBINMAX * 4 + 512, stream);

    // ---- pass 1: bin edges (LDS hist + ~100K reservation atomics) fused with layer-1 mm ----
    k_bin_mm1<<<2048, blk, 0, stream>>>(ei, E, binp, binned, BCAP,
                                        x, W1, as1, ad1, hb, ssrc, sdst, N);

    // ---- layer 1 aggregate (edge-parallel, LDS accumulators) ----
    k_agg<<<nb, blk, 0, stream>>>(binned, binp, BCAP, ssrc, sdst, hb, b1,
                                  nullptr, out, bn, bn + 64, 0, N);

    // ---- layer 2 (BN stats folded into mm preamble; final mix fused into agg) ----
    k_mm_att<<<2048, blk, 0, stream>>>(out, W2, as2, ad2, bn, bn + 64, gamma, beta,
                                       hb, ssrc, sdst, N);
    k_agg<<<nb, blk, 0, stream>>>(binned, binp, BCAP, ssrc, sdst, hb, b2,
                                  x, out, bn, bn + 64, 1, N);
}

// Round 8
// 1563.856 us; speedup vs baseline: 1.0048x; 1.0048x over previous
//
#include <hip/hip_runtime.h>
#include <math.h>

#define D 64
#define NBB 128    // blocks doing the bin pass (rest of grid runs mm1)
#define NPB 128    // nodes per bin (dst >> 7); 782 bins for N=100K
#define NBINMAX 2048

__device__ __forceinline__ float lrelu(float x, float s) { return x > 0.f ? x : s * x; }

// f32 -> bf16 round-to-nearest-even
__device__ __forceinline__ unsigned f2bf(float f) {
    unsigned b = __builtin_bit_cast(unsigned, f);
    return (b + 0x7fffu + ((b >> 16) & 1u)) >> 16;
}
__device__ __forceinline__ float bflo(unsigned u) { return __builtin_bit_cast(float, u << 16); }
__device__ __forceinline__ float bfhi(unsigned u) { return __builtin_bit_cast(float, u & 0xffff0000u); }

// Native fp atomic add (ds_add_f32 / global_atomic_add_f32): fire-and-forget,
// no CAS loop, no waitcnt chain. Round-7 postmortem: plain atomicAdd(float*)
// took the safe CAS path -> ~277 serialized cycles PER EDGE (708us k_agg).
__device__ __forceinline__ void fadd_lds(float* p, float v) { unsafeAtomicAdd(p, v); }
__device__ __forceinline__ void fadd_glb(float* p, float v) { unsafeAtomicAdd(p, v); }

// mm body (round-3 form: W column cached in registers).
__device__ __forceinline__ void mm_rows(const float* __restrict__ xin,
        const float* __restrict__ W, const float* __restrict__ a_src, const float* __restrict__ a_dst,
        const float* __restrict__ bn_sum, const float* __restrict__ bn_sumsq,
        const float* __restrict__ gamma, const float* __restrict__ beta, int apply_bn,
        unsigned* __restrict__ hb, float* __restrict__ ssrc, float* __restrict__ sdst,
        int N, int worker, int nworkers, int lane, int wv) {
    float w[D];
    #pragma unroll
    for (int k = 0; k < D; ++k) w[k] = W[k * D + lane];   // column `lane`
    float asv = a_src[lane], adv = a_dst[lane];
    float sc = 1.f, sh = 0.f;
    if (apply_bn) {
        float mu = bn_sum[lane] / (float)N;
        float var = bn_sumsq[lane] / (float)N - mu * mu;   // biased var = jnp.var
        float rs = rsqrtf(var + 1e-5f);
        sc = rs * gamma[lane];
        sh = beta[lane] - mu * sc;
    }
    for (int r = worker * 4 + wv; r < N; r += nworkers * 4) {
        float v = xin[(size_t)r * D + lane];
        if (apply_bn) { v = v * sc + sh; v = v > 0.f ? v : 0.01f * v; }
        int vi = __builtin_bit_cast(int, v);
        float a0 = 0.f, a1 = 0.f, a2 = 0.f, a3 = 0.f;   // 4 chains break FMA latency
        #pragma unroll
        for (int k = 0; k < D; k += 4) {
            float b0 = __builtin_bit_cast(float, __builtin_amdgcn_readlane(vi, k + 0));
            float b1 = __builtin_bit_cast(float, __builtin_amdgcn_readlane(vi, k + 1));
            float b2 = __builtin_bit_cast(float, __builtin_amdgcn_readlane(vi, k + 2));
            float b3 = __builtin_bit_cast(float, __builtin_amdgcn_readlane(vi, k + 3));
            a0 = fmaf(b0, w[k + 0], a0);
            a1 = fmaf(b1, w[k + 1], a1);
            a2 = fmaf(b2, w[k + 2], a2);
            a3 = fmaf(b3, w[k + 3], a3);
        }
        float acc = (a0 + a1) + (a2 + a3);
        // pack col pairs to bf16x2; even lanes store 4B (row = 32 uints = 128B)
        float accp = __shfl_xor(acc, 1, 64);
        unsigned packed = f2bf(acc) | (f2bf(accp) << 16);
        if (!(lane & 1)) hb[(size_t)r * 32 + (lane >> 1)] = packed;
        float v1 = acc * asv, v2 = acc * adv;
        #pragma unroll
        for (int off = 32; off; off >>= 1) {
            v1 += __shfl_xor(v1, off, 64);
            v2 += __shfl_xor(v2, off, 64);
        }
        if (lane == 0) { ssrc[r] = v1; sdst[r] = v2; }
    }
}

// Pass 1 fused with layer-1 mm.
// Blocks [0,NBB): bin edges by dst>>7 into per-bin contiguous regions of `binned`.
// Blocks [NBB, grid): layer-1 mm.
__global__ __launch_bounds__(256) void k_bin_mm1(const int* __restrict__ ei, int E,
        int* __restrict__ bin_ptr, int2* __restrict__ binned, int BCAP,
        const float* __restrict__ xin, const float* __restrict__ W,
        const float* __restrict__ a_src, const float* __restrict__ a_dst,
        unsigned* __restrict__ hb, float* __restrict__ ssrc, float* __restrict__ sdst, int N) {
    __shared__ int hist[NBINMAX], cur[NBINMAX];
    int tid = threadIdx.x, lane = tid & 63, wv = tid >> 6;
    if (blockIdx.x < NBB) {
        int nb = (N + NPB - 1) >> 7;
        for (int t = tid; t < nb; t += 256) hist[t] = 0;
        __syncthreads();
        int nq4 = E >> 2;
        int qpb = (nq4 + NBB - 1) / NBB;
        int q0 = blockIdx.x * qpb;
        int q1 = q0 + qpb; if (q1 > nq4) q1 = nq4;
        const int4* s4 = (const int4*)ei;
        const int4* d4 = (const int4*)(ei + E);
        // pass A: LDS histogram over bins (int atomics: native, fast)
        for (int i = q0 + tid; i < q1; i += 256) {
            int4 d = d4[i];
            atomicAdd(&hist[d.x >> 7], 1);
            atomicAdd(&hist[d.y >> 7], 1);
            atomicAdd(&hist[d.z >> 7], 1);
            atomicAdd(&hist[d.w >> 7], 1);
        }
        if (blockIdx.x == 0 && tid < (E & 3)) {
            int dd = ei[E + (nq4 << 2) + tid];
            atomicAdd(&hist[dd >> 7], 1);
        }
        __syncthreads();
        // reserve contiguous slices per bin (device atomics: one per (block,bin))
        for (int t = tid; t < nb; t += 256)
            cur[t] = hist[t] ? atomicAdd(&bin_ptr[t], hist[t]) : 0;
        __syncthreads();
        // pass B: place edges (dst re-read is L2-hot)
        for (int i = q0 + tid; i < q1; i += 256) {
            int4 s = s4[i];
            int4 d = d4[i];
            int t0 = d.x >> 7, t1 = d.y >> 7, t2 = d.z >> 7, t3 = d.w >> 7;
            int p0 = atomicAdd(&cur[t0], 1);
            int p1 = atomicAdd(&cur[t1], 1);
            int p2 = atomicAdd(&cur[t2], 1);
            int p3 = atomicAdd(&cur[t3], 1);
            if (p0 < BCAP) binned[(size_t)t0 * BCAP + p0] = make_int2(s.x, d.x);
            if (p1 < BCAP) binned[(size_t)t1 * BCAP + p1] = make_int2(s.y, d.y);
            if (p2 < BCAP) binned[(size_t)t2 * BCAP + p2] = make_int2(s.z, d.z);
            if (p3 < BCAP) binned[(size_t)t3 * BCAP + p3] = make_int2(s.w, d.w);
        }
        if (blockIdx.x == 0 && tid < (E & 3)) {
            int i = (nq4 << 2) + tid;
            int ss = ei[i], dd = ei[E + i];
            int t = dd >> 7;
            int p = atomicAdd(&cur[t], 1);
            if (p < BCAP) binned[(size_t)t * BCAP + p] = make_int2(ss, dd);
        }
    } else {
        mm_rows(xin, W, a_src, a_dst, nullptr, nullptr, nullptr, nullptr, 0,
                hb, ssrc, sdst, N, blockIdx.x - NBB, gridDim.x - NBB, lane, wv);
    }
}

// standalone layer-2 mm (BN folded in)
__global__ __launch_bounds__(256) void k_mm_att(const float* __restrict__ xin,
        const float* __restrict__ W, const float* __restrict__ a_src, const float* __restrict__ a_dst,
        const float* __restrict__ bn_sum, const float* __restrict__ bn_sumsq,
        const float* __restrict__ gamma, const float* __restrict__ beta,
        unsigned* __restrict__ hb, float* __restrict__ ssrc, float* __restrict__ sdst, int N) {
    int tid = threadIdx.x, lane = tid & 63, wv = tid >> 6;
    mm_rows(xin, W, a_src, a_dst, bn_sum, bn_sumsq, gamma, beta, 1,
            hb, ssrc, sdst, N, blockIdx.x, gridDim.x, lane, wv);
}

// EDGE-PARALLEL aggregation (round-7 structure, round-8 native fp atomics):
// one block per 128-dst-node bin; edges streamed flat (coalesced, no dependent
// address chains); weighted h-rows ds_add_f32'ed into a 128x64 LDS tile;
// z is another LDS accumulator. 16-lane group per edge; x4 unrolled.
// mode 0: out = agg/z + bias (fp32), accumulate BN col sums.
// mode 1: out = 0.5*(x + agg/z + bias)
__global__ __launch_bounds__(256) void k_agg(const int2* __restrict__ binned,
        const int* __restrict__ bin_ptr, int BCAP,
        const float* __restrict__ ssrc, const float* __restrict__ sdst,
        const unsigned* __restrict__ hb, const float* __restrict__ bias,
        const float* __restrict__ x, float* __restrict__ out,
        float* __restrict__ bn_sum, float* __restrict__ bn_sumsq, int mode, int N) {
    __shared__ float accs[NPB][68];    // 34.8KB, padded stride
    __shared__ float zz[NPB];
    __shared__ float sds[NPB];
    __shared__ float sbn1[D], sbn2[D];
    int tid = threadIdx.x;
    int sl = tid & 15;                 // lane in group: cols 4sl..4sl+3
    int g = tid >> 4;                  // group 0..15
    int b = blockIdx.x;
    int n0 = b << 7;

    for (int i = tid; i < NPB * 68; i += 256) ((float*)accs)[i] = 0.f;
    if (tid < NPB) {
        zz[tid] = 0.f;
        int nd = n0 + tid;
        sds[tid] = (nd < N) ? sdst[nd] : 0.f;
    }
    if (mode == 0 && tid < D) { sbn1[tid] = 0.f; sbn2[tid] = 0.f; }
    __syncthreads();

    int m = bin_ptr[b]; if (m > BCAP) m = BCAP;
    const int2* base = binned + (size_t)b * BCAP;
    const uint2* h2 = (const uint2*)hb;           // row = 16 uint2

    for (int i = g; i < m; i += 64) {
        int i1 = i + 16, i2 = i + 32, i3 = i + 48;
        bool v1 = i1 < m, v2 = i2 < m, v3 = i3 < m;
        int2 E0 = base[i];
        int2 E1 = base[v1 ? i1 : i];
        int2 E2 = base[v2 ? i2 : i];
        int2 E3 = base[v3 ? i3 : i];
        // independent gathers: 4 ssrc (broadcast) + 4 h-rows in flight
        float q0 = ssrc[E0.x], q1 = ssrc[E1.x], q2 = ssrc[E2.x], q3 = ssrc[E3.x];
        uint2 h0 = h2[(size_t)E0.x * 16 + sl];
        uint2 h1 = h2[(size_t)E1.x * 16 + sl];
        uint2 hh2 = h2[(size_t)E2.x * 16 + sl];
        uint2 h3 = h2[(size_t)E3.x * 16 + sl];
        int d0 = E0.y & 127, d1 = E1.y & 127, d2 = E2.y & 127, d3 = E3.y & 127;
        float e0 = __expf(lrelu(q0 + sds[d0], 0.2f));
        float e1 = __expf(lrelu(q1 + sds[d1], 0.2f));
        float e2 = __expf(lrelu(q2 + sds[d2], 0.2f));
        float e3 = __expf(lrelu(q3 + sds[d3], 0.2f));
        int c = sl << 2;
        {
            if (sl == 0) fadd_lds(&zz[d0], e0);
            fadd_lds(&accs[d0][c + 0], e0 * bflo(h0.x));
            fadd_lds(&accs[d0][c + 1], e0 * bfhi(h0.x));
            fadd_lds(&accs[d0][c + 2], e0 * bflo(h0.y));
            fadd_lds(&accs[d0][c + 3], e0 * bfhi(h0.y));
        }
        if (v1) {
            if (sl == 0) fadd_lds(&zz[d1], e1);
            fadd_lds(&accs[d1][c + 0], e1 * bflo(h1.x));
            fadd_lds(&accs[d1][c + 1], e1 * bfhi(h1.x));
            fadd_lds(&accs[d1][c + 2], e1 * bflo(h1.y));
            fadd_lds(&accs[d1][c + 3], e1 * bfhi(h1.y));
        }
        if (v2) {
            if (sl == 0) fadd_lds(&zz[d2], e2);
            fadd_lds(&accs[d2][c + 0], e2 * bflo(hh2.x));
            fadd_lds(&accs[d2][c + 1], e2 * bfhi(hh2.x));
            fadd_lds(&accs[d2][c + 2], e2 * bflo(hh2.y));
            fadd_lds(&accs[d2][c + 3], e2 * bfhi(hh2.y));
        }
        if (v3) {
            if (sl == 0) fadd_lds(&zz[d3], e3);
            fadd_lds(&accs[d3][c + 0], e3 * bflo(h3.x));
            fadd_lds(&accs[d3][c + 1], e3 * bfhi(h3.x));
            fadd_lds(&accs[d3][c + 2], e3 * bflo(h3.y));
            fadd_lds(&accs[d3][c + 3], e3 * bfhi(h3.y));
        }
    }
    __syncthreads();

    // epilogue: each group handles nodes g, g+16, ..., g+112
    float4 s1 = make_float4(0, 0, 0, 0), s2 = make_float4(0, 0, 0, 0);
    int c = sl << 2;
    for (int ii = g; ii < NPB; ii += 16) {
        int nd = n0 + ii;
        if (nd < N) {
            float ssn = ssrc[nd];
            float es = __expf(lrelu(ssn + sds[ii], 0.2f));
            float zt = zz[ii] + es;
            uint2 hv = h2[(size_t)nd * 16 + sl];   // self-loop row (coalesced)
            float inv = 1.f / zt;
            float4 b4 = ((const float4*)bias)[sl];
            float4 v;
            v.x = fmaf(es, bflo(hv.x), accs[ii][c + 0]) * inv + b4.x;
            v.y = fmaf(es, bfhi(hv.x), accs[ii][c + 1]) * inv + b4.y;
            v.z = fmaf(es, bflo(hv.y), accs[ii][c + 2]) * inv + b4.z;
            v.w = fmaf(es, bfhi(hv.y), accs[ii][c + 3]) * inv + b4.w;
            if (mode == 0) {
                ((float4*)out)[(size_t)nd * 16 + sl] = v;
                s1.x += v.x; s1.y += v.y; s1.z += v.z; s1.w += v.w;
                s2.x += v.x * v.x; s2.y += v.y * v.y;
                s2.z += v.z * v.z; s2.w += v.w * v.w;
            } else {
                float4 xv = ((const float4*)x)[(size_t)nd * 16 + sl];
                v.x = 0.5f * (xv.x + v.x); v.y = 0.5f * (xv.y + v.y);
                v.z = 0.5f * (xv.z + v.z); v.w = 0.5f * (xv.w + v.w);
                ((float4*)out)[(size_t)nd * 16 + sl] = v;
            }
        }
    }
    if (mode == 0) {
        fadd_lds(&sbn1[c + 0], s1.x); fadd_lds(&sbn1[c + 1], s1.y);
        fadd_lds(&sbn1[c + 2], s1.z); fadd_lds(&sbn1[c + 3], s1.w);
        fadd_lds(&sbn2[c + 0], s2.x); fadd_lds(&sbn2[c + 1], s2.y);
        fadd_lds(&sbn2[c + 2], s2.z); fadd_lds(&sbn2[c + 3], s2.w);
        __syncthreads();
        if (tid < D) {
            fadd_glb(&bn_sum[tid], sbn1[tid]);
            fadd_glb(&bn_sumsq[tid], sbn2[tid]);
        }
    }
}

extern "C" void kernel_launch(void* const* d_in, const int* in_sizes, int n_in,
                              void* d_out, int out_size, void* d_ws, size_t ws_size,
                              hipStream_t stream) {
    const float* x     = (const float*)d_in[0];
    const float* W1    = (const float*)d_in[1];
    const float* as1   = (const float*)d_in[2];
    const float* ad1   = (const float*)d_in[3];
    const float* b1    = (const float*)d_in[4];
    const float* gamma = (const float*)d_in[5];
    const float* beta  = (const float*)d_in[6];
    const float* W2    = (const float*)d_in[7];
    const float* as2   = (const float*)d_in[8];
    const float* ad2   = (const float*)d_in[9];
    const float* b2    = (const float*)d_in[10];
    const int*   ei    = (const int*)d_in[11];
    int N = in_sizes[0] / D;
    int E = in_sizes[11] / 2;
    float* out = (float*)d_out;          // layer-1 output buffer (fp32), then final

    float* ws = (float*)d_ws;
    unsigned* hb = (unsigned*)ws;                 // bf16-packed h: N*32 uints (12.8MB)
    float* ssrc = (float*)(hb + (size_t)N * 32);
    float* sdst = ssrc + N;
    int* binp   = (int*)(sdst + N);               // NBINMAX bin totals (memset)
    float* bn   = (float*)(binp + NBINMAX);       // 128: sum(64) | sumsq(64) (memset, contiguous)
    int2* binned = (int2*)(bn + 128);             // nb*BCAP edges (~18MB, lives in ws)

    int nb = (N + NPB - 1) >> 7;                  // 782 bins for N=100K
    int BCAP = E / nb + (E / nb) / 4 + 256;       // avg + 25% + slack

    dim3 blk(256);

    // zero bin totals + bn in one async memset
    hipMemsetAsync(binp, 0, NBINMAX * 4 + 512, stream);

    // ---- pass 1: bin edges (LDS hist + ~100K reservation atomics) fused with layer-1 mm ----
    k_bin_mm1<<<2048, blk, 0, stream>>>(ei, E, binp, binned, BCAP,
                                        x, W1, as1, ad1, hb, ssrc, sdst, N);

    // ---- layer 1 aggregate (edge-parallel, LDS accumulators) ----
    k_agg<<<nb, blk, 0, stream>>>(binned, binp, BCAP, ssrc, sdst, hb, b1,
                                  nullptr, out, bn, bn + 64, 0, N);

    // ---- layer 2 (BN stats folded into mm preamble; final mix fused into agg) ----
    k_mm_att<<<2048, blk, 0, stream>>>(out, W2, as2, ad2, bn, bn + 64, gamma, beta,
                                       hb, ssrc, sdst, N);
    k_agg<<<nb, blk, 0, stream>>>(binned, binp, BCAP, ssrc, sdst, hb, b2,
                                  x, out, bn, bn + 64, 1, N);
}

// Round 10
// 298.937 us; speedup vs baseline: 5.2564x; 5.2314x over previous
//
#include <hip/hip_runtime.h>
#include <math.h>

#define D 64
#define CAP 64     // bucket = 64 ints = 256B; P(deg>64)~5e-16 for Poisson(16)
#define NBB 128    // blocks doing the bin pass (rest of grid runs mm1)
#define NPB 256    // nodes per bin (dst >> 8); 391 bins for N=100K

__device__ __forceinline__ float lrelu(float x, float s) { return x > 0.f ? x : s * x; }

// f32 -> bf16 round-to-nearest-even
__device__ __forceinline__ unsigned f2bf(float f) {
    unsigned b = __builtin_bit_cast(unsigned, f);
    return (b + 0x7fffu + ((b >> 16) & 1u)) >> 16;
}
__device__ __forceinline__ float bflo(unsigned u) { return __builtin_bit_cast(float, u << 16); }
__device__ __forceinline__ float bfhi(unsigned u) { return __builtin_bit_cast(float, u & 0xffff0000u); }

// mm body (round-3 form: W column cached in registers).
__device__ __forceinline__ void mm_rows(const float* __restrict__ xin,
        const float* __restrict__ W, const float* __restrict__ a_src, const float* __restrict__ a_dst,
        const float* __restrict__ bn_sum, const float* __restrict__ bn_sumsq,
        const float* __restrict__ gamma, const float* __restrict__ beta, int apply_bn,
        unsigned* __restrict__ hb, float* __restrict__ ssrc, float* __restrict__ sdst,
        int N, int worker, int nworkers, int lane, int wv) {
    float w[D];
    #pragma unroll
    for (int k = 0; k < D; ++k) w[k] = W[k * D + lane];   // column `lane`
    float asv = a_src[lane], adv = a_dst[lane];
    float sc = 1.f, sh = 0.f;
    if (apply_bn) {
        float mu = bn_sum[lane] / (float)N;
        float var = bn_sumsq[lane] / (float)N - mu * mu;   // biased var = jnp.var
        float rs = rsqrtf(var + 1e-5f);
        sc = rs * gamma[lane];
        sh = beta[lane] - mu * sc;
    }
    for (int r = worker * 4 + wv; r < N; r += nworkers * 4) {
        float v = xin[(size_t)r * D + lane];
        if (apply_bn) { v = v * sc + sh; v = v > 0.f ? v : 0.01f * v; }
        int vi = __builtin_bit_cast(int, v);
        float a0 = 0.f, a1 = 0.f, a2 = 0.f, a3 = 0.f;   // 4 chains break FMA latency
        #pragma unroll
        for (int k = 0; k < D; k += 4) {
            float b0 = __builtin_bit_cast(float, __builtin_amdgcn_readlane(vi, k + 0));
            float b1 = __builtin_bit_cast(float, __builtin_amdgcn_readlane(vi, k + 1));
            float b2 = __builtin_bit_cast(float, __builtin_amdgcn_readlane(vi, k + 2));
            float b3 = __builtin_bit_cast(float, __builtin_amdgcn_readlane(vi, k + 3));
            a0 = fmaf(b0, w[k + 0], a0);
            a1 = fmaf(b1, w[k + 1], a1);
            a2 = fmaf(b2, w[k + 2], a2);
            a3 = fmaf(b3, w[k + 3], a3);
        }
        float acc = (a0 + a1) + (a2 + a3);
        // pack col pairs to bf16x2; even lanes store 4B (row = 32 uints = 128B)
        float accp = __shfl_xor(acc, 1, 64);
        unsigned packed = f2bf(acc) | (f2bf(accp) << 16);
        if (!(lane & 1)) hb[(size_t)r * 32 + (lane >> 1)] = packed;
        float v1 = acc * asv, v2 = acc * adv;
        #pragma unroll
        for (int off = 32; off; off >>= 1) {
            v1 += __shfl_xor(v1, off, 64);
            v2 += __shfl_xor(v2, off, 64);
        }
        if (lane == 0) { ssrc[r] = v1; sdst[r] = v2; }
    }
}

// Pass 1 fused with layer-1 mm.
// Blocks [0,NBB): bin edges by dst>>8 into per-bin regions of `binned`,
//   entries PACKED to 4B (src | dstLocal<<17) — halves the scatter-amplified
//   write stream (rounds 3-6 pole: 64 lanes -> ~64 sectors, 8B payload each).
// Blocks [NBB, grid): layer-1 mm.
__global__ __launch_bounds__(256) void k_bin_mm1(const int* __restrict__ ei, int E,
        int* __restrict__ bin_ptr, unsigned* __restrict__ binned, int BCAP,
        const float* __restrict__ xin, const float* __restrict__ W,
        const float* __restrict__ a_src, const float* __restrict__ a_dst,
        unsigned* __restrict__ hb, float* __restrict__ ssrc, float* __restrict__ sdst, int N) {
    __shared__ int hist[512], cur[512];
    int tid = threadIdx.x, lane = tid & 63, wv = tid >> 6;
    if (blockIdx.x < NBB) {
        int nb = (N + NPB - 1) >> 8;
        for (int t = tid; t < nb; t += 256) hist[t] = 0;
        __syncthreads();
        int nq4 = E >> 2;
        int qpb = (nq4 + NBB - 1) / NBB;
        int q0 = blockIdx.x * qpb;
        int q1 = q0 + qpb; if (q1 > nq4) q1 = nq4;
        const int4* s4 = (const int4*)ei;
        const int4* d4 = (const int4*)(ei + E);
        // pass A: LDS histogram over bins (int atomics: native, fast)
        for (int i = q0 + tid; i < q1; i += 256) {
            int4 d = d4[i];
            atomicAdd(&hist[d.x >> 8], 1);
            atomicAdd(&hist[d.y >> 8], 1);
            atomicAdd(&hist[d.z >> 8], 1);
            atomicAdd(&hist[d.w >> 8], 1);
        }
        if (blockIdx.x == 0 && tid < (E & 3)) {
            int dd = ei[E + (nq4 << 2) + tid];
            atomicAdd(&hist[dd >> 8], 1);
        }
        __syncthreads();
        // reserve contiguous slices per bin (device atomics: one per (block,bin))
        for (int t = tid; t < nb; t += 256)
            cur[t] = hist[t] ? atomicAdd(&bin_ptr[t], hist[t]) : 0;
        __syncthreads();
        // pass B: place packed edges (dst re-read is L2-hot)
        for (int i = q0 + tid; i < q1; i += 256) {
            int4 s = s4[i];
            int4 d = d4[i];
            int t0 = d.x >> 8, t1 = d.y >> 8, t2 = d.z >> 8, t3 = d.w >> 8;
            int p0 = atomicAdd(&cur[t0], 1);
            int p1 = atomicAdd(&cur[t1], 1);
            int p2 = atomicAdd(&cur[t2], 1);
            int p3 = atomicAdd(&cur[t3], 1);
            if (p0 < BCAP) binned[(size_t)t0 * BCAP + p0] = (unsigned)s.x | ((unsigned)(d.x & 255) << 17);
            if (p1 < BCAP) binned[(size_t)t1 * BCAP + p1] = (unsigned)s.y | ((unsigned)(d.y & 255) << 17);
            if (p2 < BCAP) binned[(size_t)t2 * BCAP + p2] = (unsigned)s.z | ((unsigned)(d.z & 255) << 17);
            if (p3 < BCAP) binned[(size_t)t3 * BCAP + p3] = (unsigned)s.w | ((unsigned)(d.w & 255) << 17);
        }
        if (blockIdx.x == 0 && tid < (E & 3)) {
            int i = (nq4 << 2) + tid;
            int ss = ei[i], dd = ei[E + i];
            int t = dd >> 8;
            int p = atomicAdd(&cur[t], 1);
            if (p < BCAP) binned[(size_t)t * BCAP + p] = (unsigned)ss | ((unsigned)(dd & 255) << 17);
        }
    } else {
        mm_rows(xin, W, a_src, a_dst, nullptr, nullptr, nullptr, nullptr, 0,
                hb, ssrc, sdst, N, blockIdx.x - NBB, gridDim.x - NBB, lane, wv);
    }
}

// Pass 2: one block per bin (256 consecutive dst nodes). Per-edge slot counters
// in LDS (int atomics, native); col writes land in the block's 64KB window.
__global__ __launch_bounds__(256) void k_scatter(const unsigned* __restrict__ binned,
        const int* __restrict__ bin_ptr, int BCAP,
        int* __restrict__ col, int* __restrict__ cnt, int N) {
    __shared__ int cur[NPB];
    int tid = threadIdx.x;
    int b = blockIdx.x;
    cur[tid] = 0;
    __syncthreads();
    int cntb = bin_ptr[b]; if (cntb > BCAP) cntb = BCAP;
    const unsigned* base = binned + (size_t)b * BCAP;
    for (int i = tid; i < cntb; i += 256) {
        unsigned e = base[i];
        int dl = (int)(e >> 17);
        int k = atomicAdd(&cur[dl], 1);
        if (k < CAP) col[((size_t)((b << 8) + dl) << 6) + k] = (int)(e & 0x1FFFFu);
    }
    __syncthreads();
    int node = (b << 8) + tid;
    if (node < N) cnt[node] = cur[tid];
}

// standalone layer-2 mm (BN folded in)
__global__ __launch_bounds__(256) void k_mm_att(const float* __restrict__ xin,
        const float* __restrict__ W, const float* __restrict__ a_src, const float* __restrict__ a_dst,
        const float* __restrict__ bn_sum, const float* __restrict__ bn_sumsq,
        const float* __restrict__ gamma, const float* __restrict__ beta,
        unsigned* __restrict__ hb, float* __restrict__ ssrc, float* __restrict__ sdst, int N) {
    int tid = threadIdx.x, lane = tid & 63, wv = tid >> 6;
    mm_rows(xin, W, a_src, a_dst, bn_sum, bn_sumsq, gamma, beta, 1,
            hb, ssrc, sdst, N, blockIdx.x, gridDim.x, lane, wv);
}

// issue quad q of node's col list into named register quad P
#define AGG_ISSUE(P, q) { \
    int sA_ = __shfl(sal0.x, (q), 16), sB_ = __shfl(sal0.y, (q), 16); \
    int sC_ = __shfl(sal0.z, (q), 16), sD_ = __shfl(sal0.w, (q), 16); \
    P##A = h2[(size_t)sA_ * 16 + sl]; P##B = h2[(size_t)sB_ * 16 + sl]; \
    P##C = h2[(size_t)sC_ * 16 + sl]; P##D = h2[(size_t)sD_ * 16 + sl]; }

// consume register quad P as quad index i
#define AGG_CONSUME(P, i) { \
    float eA_ = __shfl(e0, (i), 16), eB_ = __shfl(e1, (i), 16); \
    float eC_ = __shfl(e2, (i), 16), eD_ = __shfl(e3, (i), 16); \
    acc.x = fmaf(eA_, bflo(P##A.x), acc.x); acc.y = fmaf(eA_, bfhi(P##A.x), acc.y); \
    acc.z = fmaf(eA_, bflo(P##A.y), acc.z); acc.w = fmaf(eA_, bfhi(P##A.y), acc.w); \
    acc.x = fmaf(eB_, bflo(P##B.x), acc.x); acc.y = fmaf(eB_, bfhi(P##B.x), acc.y); \
    acc.z = fmaf(eB_, bflo(P##B.y), acc.z); acc.w = fmaf(eB_, bfhi(P##B.y), acc.w); \
    acc.x = fmaf(eC_, bflo(P##C.x), acc.x); acc.y = fmaf(eC_, bfhi(P##C.x), acc.y); \
    acc.z = fmaf(eC_, bflo(P##C.y), acc.z); acc.w = fmaf(eC_, bfhi(P##C.y), acc.w); \
    acc.x = fmaf(eD_, bflo(P##D.x), acc.x); acc.y = fmaf(eD_, bfhi(P##D.x), acc.y); \
    acc.z = fmaf(eD_, bflo(P##D.y), acc.z); acc.w = fmaf(eD_, bfhi(P##D.y), acc.w); }

// 16-lane sub-group per node (4 nodes/wave), DEPTH-3 software-pipelined gather
// loop (round 6 was depth-2: 80->73.5us; counters still showed avg ~1.8
// gathers in flight/wave). Also: next-node ssrc gathers (stage B) issued
// BEFORE the quad loop (round 6 issued them after — serial exposure).
// mode 0: out = agg/z + bias (fp32), accumulate BN col sums.
// mode 1: out = 0.5*(x + agg/z + bias)
__global__ __launch_bounds__(256) void k_csr_agg(const int* __restrict__ col,
        const int* __restrict__ cnt,
        const float* __restrict__ ssrc, const float* __restrict__ sdst,
        const unsigned* __restrict__ hb, const float* __restrict__ bias,
        const float* __restrict__ x, float* __restrict__ out,
        float* __restrict__ bn_sum, float* __restrict__ bn_sumsq, int mode, int N) {
    __shared__ float sbn1[D], sbn2[D];
    int tid = threadIdx.x;
    int lane = tid & 63;
    int sl = lane & 15;        // lane within sub-group; covers cols 4sl..4sl+3
    if (mode == 0) {
        if (tid < D) { sbn1[tid] = 0.f; sbn2[tid] = 0.f; }
        __syncthreads();
    }
    int sgid = (blockIdx.x * 256 + tid) >> 4;     // global sub-group id
    int stride = gridDim.x * 16;                  // sub-groups per grid
    const uint2* h2 = (const uint2*)hb;           // row = 16 uint2
    float4 s1 = make_float4(0, 0, 0, 0), s2 = make_float4(0, 0, 0, 0);

    // stage A: cnt/col(int4)/ssrc[n]/sdst[n]; clamp OOR node to sgid (valid)
    auto loadA = [&](int node, int& dg, int4& sal, float& ssn, float& sdn) {
        int nn = (node < N) ? node : sgid;
        int dgl = cnt[nn]; dgl = dgl > CAP ? CAP : dgl;
        int4 c = ((const int4*)(col + ((size_t)nn << 6)))[sl];
        int eb = sl << 2;
        sal.x = (eb + 0 < dgl) ? c.x : nn;        // clamped: valid node id
        sal.y = (eb + 1 < dgl) ? c.y : nn;
        sal.z = (eb + 2 < dgl) ? c.z : nn;
        sal.w = (eb + 3 < dgl) ? c.w : nn;
        dg = dgl; ssn = ssrc[nn]; sdn = sdst[nn];
    };

    if (sgid < N) {
        int dg0, dg1; int4 sal0, sal1;
        float ssn0, sdn0, ssn1, sdn1;
        float4 g0;
        loadA(sgid,          dg0, sal0, ssn0, sdn0);
        loadA(sgid + stride, dg1, sal1, ssn1, sdn1);
        g0.x = ssrc[sal0.x]; g0.y = ssrc[sal0.y];
        g0.z = ssrc[sal0.z]; g0.w = ssrc[sal0.w];

        for (int n = sgid; n < N; n += stride) {
            // ---- C-top: self row + quads 0..2 (depend only on sal0) ----
            uint2 hv = h2[(size_t)n * 16 + sl];
            int Q = dg0 > 0 ? ((dg0 + 3) >> 2) : 1;
            uint2 p0A, p0B, p0C, p0D, p1A, p1B, p1C, p1D, p2A, p2B, p2C, p2D;
            AGG_ISSUE(p0, 0)
            if (Q > 1) AGG_ISSUE(p1, 1)
            if (Q > 2) AGG_ISSUE(p2, 2)

            // ---- A(n+2s): far-ahead loads (consumed 2 nodes later) ----
            int dg2; int4 sal2; float ssn2, sdn2;
            loadA(n + 2 * stride, dg2, sal2, ssn2, sdn2);

            // ---- B(n+s): next node's logit gathers, issued EARLY ----
            float4 g1;
            g1.x = ssrc[sal1.x]; g1.y = ssrc[sal1.y];
            g1.z = ssrc[sal1.z]; g1.w = ssrc[sal1.w];

            // ---- VALU under gather latency: e's, z-reduce, acc init ----
            int eb = sl << 2;
            float e0 = (eb + 0 < dg0) ? __expf(lrelu(g0.x + sdn0, 0.2f)) : 0.f;
            float e1 = (eb + 1 < dg0) ? __expf(lrelu(g0.y + sdn0, 0.2f)) : 0.f;
            float e2 = (eb + 2 < dg0) ? __expf(lrelu(g0.z + sdn0, 0.2f)) : 0.f;
            float e3 = (eb + 3 < dg0) ? __expf(lrelu(g0.w + sdn0, 0.2f)) : 0.f;
            float z = (e0 + e1) + (e2 + e3);
            #pragma unroll
            for (int off = 1; off <= 8; off <<= 1) z += __shfl_xor(z, off, 64);
            float es = __expf(lrelu(ssn0 + sdn0, 0.2f));
            z += es;
            float4 acc;
            acc.x = es * bflo(hv.x); acc.y = es * bfhi(hv.x);
            acc.z = es * bflo(hv.y); acc.w = es * bfhi(hv.y);

            // ---- depth-3 pipelined quad loop (rotating named quads) ----
            int i = 0;
            while (true) {
                AGG_CONSUME(p0, i)
                if (i + 3 < Q) AGG_ISSUE(p0, i + 3)
                if (++i >= Q) break;
                AGG_CONSUME(p1, i)
                if (i + 3 < Q) AGG_ISSUE(p1, i + 3)
                if (++i >= Q) break;
                AGG_CONSUME(p2, i)
                if (i + 3 < Q) AGG_ISSUE(p2, i + 3)
                if (++i >= Q) break;
            }

            // epilogue — no cross-lane reduce; all 16 lanes store
            float inv = 1.f / z;
            float4 b4 = ((const float4*)bias)[sl];
            float4 v;
            v.x = acc.x * inv + b4.x; v.y = acc.y * inv + b4.y;
            v.z = acc.z * inv + b4.z; v.w = acc.w * inv + b4.w;
            if (mode == 0) {
                ((float4*)out)[(size_t)n * 16 + sl] = v;
                s1.x += v.x; s1.y += v.y; s1.z += v.z; s1.w += v.w;
                s2.x += v.x * v.x; s2.y += v.y * v.y;
                s2.z += v.z * v.z; s2.w += v.w * v.w;
            } else {
                float4 xv = ((const float4*)x)[(size_t)n * 16 + sl];
                v.x = 0.5f * (xv.x + v.x); v.y = 0.5f * (xv.y + v.y);
                v.z = 0.5f * (xv.z + v.z); v.w = 0.5f * (xv.w + v.w);
                ((float4*)out)[(size_t)n * 16 + sl] = v;
            }
            // shift pipeline
            dg0 = dg1; sal0 = sal1; ssn0 = ssn1; sdn0 = sdn1; g0 = g1;
            dg1 = dg2; sal1 = sal2; ssn1 = ssn2; sdn1 = sdn2;
        }
    }
    if (mode == 0) {
        int c = sl * 4;       // block-level epilogue only: 16 ops/thread once per block
        atomicAdd(&sbn1[c + 0], s1.x); atomicAdd(&sbn1[c + 1], s1.y);
        atomicAdd(&sbn1[c + 2], s1.z); atomicAdd(&sbn1[c + 3], s1.w);
        atomicAdd(&sbn2[c + 0], s2.x); atomicAdd(&sbn2[c + 1], s2.y);
        atomicAdd(&sbn2[c + 2], s2.z); atomicAdd(&sbn2[c + 3], s2.w);
        __syncthreads();
        if (tid < D) {
            atomicAdd(&bn_sum[tid], sbn1[tid]);
            atomicAdd(&bn_sumsq[tid], sbn2[tid]);
        }
    }
}

extern "C" void kernel_launch(void* const* d_in, const int* in_sizes, int n_in,
                              void* d_out, int out_size, void* d_ws, size_t ws_size,
                              hipStream_t stream) {
    const float* x     = (const float*)d_in[0];
    const float* W1    = (const float*)d_in[1];
    const float* as1   = (const float*)d_in[2];
    const float* ad1   = (const float*)d_in[3];
    const float* b1    = (const float*)d_in[4];
    const float* gamma = (const float*)d_in[5];
    const float* beta  = (const float*)d_in[6];
    const float* W2    = (const float*)d_in[7];
    const float* as2   = (const float*)d_in[8];
    const float* ad2   = (const float*)d_in[9];
    const float* b2    = (const float*)d_in[10];
    const int*   ei    = (const int*)d_in[11];
    int N = in_sizes[0] / D;
    int E = in_sizes[11] / 2;
    float* out = (float*)d_out;          // layer-1 output buffer (fp32), then final

    float* ws = (float*)d_ws;
    unsigned* hb = (unsigned*)ws;                 // bf16-packed h: N*32 uints (12.8MB)
    float* ssrc = (float*)(hb + (size_t)N * 32);
    float* sdst = ssrc + N;
    int* cnt    = (int*)(sdst + N);               // N exact degrees (written by k_scatter)
    int* binp   = cnt + N;                        // 512 bin totals (memset)
    float* bn   = (float*)(binp + 512);           // 128: sum(64) | sumsq(64) (memset, contiguous)
    int* colarr = (int*)(bn + 128);               // N*CAP (25.6MB)

    int nb = (N + NPB - 1) >> 8;                  // 391 bins for N=100K
    int BCAP = E / nb + (E / nb) / 4 + 256;       // avg + 25% + slack
    // packed binned aliases d_out (dead before agg1 overwrites out).
    // out_size is in ELEMENTS (fp32); binned uses nb*BCAP uints = same count.
    if ((size_t)nb * BCAP > (size_t)out_size) BCAP = (int)((size_t)out_size / (size_t)nb);
    unsigned* binned = (unsigned*)d_out;

    dim3 blk(256);

    // zero bin totals + bn in one async memset
    hipMemsetAsync(binp, 0, 512 * 4 + 512, stream);

    // ---- pass 1: bin edges (packed 4B) fused with layer-1 mm ----
    k_bin_mm1<<<2048, blk, 0, stream>>>(ei, E, binp, binned, BCAP,
                                        x, W1, as1, ad1, hb, ssrc, sdst, N);

    // ---- pass 2: bins -> col/cnt, all per-edge atomics in LDS (int, native) ----
    k_scatter<<<nb, blk, 0, stream>>>(binned, binp, BCAP, colarr, cnt, N);

    // ---- layer 1 aggregate ----
    k_csr_agg<<<2048, blk, 0, stream>>>(colarr, cnt, ssrc, sdst, hb, b1,
                                        nullptr, out, bn, bn + 64, 0, N);

    // ---- layer 2 (BN stats folded into mm preamble; final mix fused into agg) ----
    k_mm_att<<<2048, blk, 0, stream>>>(out, W2, as2, ad2, bn, bn + 64, gamma, beta,
                                       hb, ssrc, sdst, N);
    k_csr_agg<<<2048, blk, 0, stream>>>(colarr, cnt, ssrc, sdst, hb, b2,
                                        x, out, bn, bn + 64, 1, N);
}

// Round 11
// 286.067 us; speedup vs baseline: 5.4929x; 1.0450x over previous
//
#include <hip/hip_runtime.h>
#include <math.h>

#define D 64
#define CAP 64     // per-node bucket: 64 edges; P(deg>64)~5e-16 for Poisson(16)
#define NBB 128    // blocks doing the bin pass (rest of grid runs mm1)
#define NPB 64     // nodes per bin (dst >> 6); 1563 bins for N=100K
#define NBINMAX 2048

__device__ __forceinline__ float lrelu(float x, float s) { return x > 0.f ? x : s * x; }

// f32 -> bf16 round-to-nearest-even
__device__ __forceinline__ unsigned f2bf(float f) {
    unsigned b = __builtin_bit_cast(unsigned, f);
    return (b + 0x7fffu + ((b >> 16) & 1u)) >> 16;
}
__device__ __forceinline__ float bflo(unsigned u) { return __builtin_bit_cast(float, u << 16); }
__device__ __forceinline__ float bfhi(unsigned u) { return __builtin_bit_cast(float, u & 0xffff0000u); }

// mm body (round-3 form: W column cached in registers).
__device__ __forceinline__ void mm_rows(const float* __restrict__ xin,
        const float* __restrict__ W, const float* __restrict__ a_src, const float* __restrict__ a_dst,
        const float* __restrict__ bn_sum, const float* __restrict__ bn_sumsq,
        const float* __restrict__ gamma, const float* __restrict__ beta, int apply_bn,
        unsigned* __restrict__ hb, float* __restrict__ ssrc, float* __restrict__ sdst,
        int N, int worker, int nworkers, int lane, int wv) {
    float w[D];
    #pragma unroll
    for (int k = 0; k < D; ++k) w[k] = W[k * D + lane];   // column `lane`
    float asv = a_src[lane], adv = a_dst[lane];
    float sc = 1.f, sh = 0.f;
    if (apply_bn) {
        float mu = bn_sum[lane] / (float)N;
        float var = bn_sumsq[lane] / (float)N - mu * mu;   // biased var = jnp.var
        float rs = rsqrtf(var + 1e-5f);
        sc = rs * gamma[lane];
        sh = beta[lane] - mu * sc;
    }
    for (int r = worker * 4 + wv; r < N; r += nworkers * 4) {
        float v = xin[(size_t)r * D + lane];
        if (apply_bn) { v = v * sc + sh; v = v > 0.f ? v : 0.01f * v; }
        int vi = __builtin_bit_cast(int, v);
        float a0 = 0.f, a1 = 0.f, a2 = 0.f, a3 = 0.f;   // 4 chains break FMA latency
        #pragma unroll
        for (int k = 0; k < D; k += 4) {
            float b0 = __builtin_bit_cast(float, __builtin_amdgcn_readlane(vi, k + 0));
            float b1 = __builtin_bit_cast(float, __builtin_amdgcn_readlane(vi, k + 1));
            float b2 = __builtin_bit_cast(float, __builtin_amdgcn_readlane(vi, k + 2));
            float b3 = __builtin_bit_cast(float, __builtin_amdgcn_readlane(vi, k + 3));
            a0 = fmaf(b0, w[k + 0], a0);
            a1 = fmaf(b1, w[k + 1], a1);
            a2 = fmaf(b2, w[k + 2], a2);
            a3 = fmaf(b3, w[k + 3], a3);
        }
        float acc = (a0 + a1) + (a2 + a3);
        // pack col pairs to bf16x2; even lanes store 4B (row = 32 uints = 128B)
        float accp = __shfl_xor(acc, 1, 64);
        unsigned packed = f2bf(acc) | (f2bf(accp) << 16);
        if (!(lane & 1)) hb[(size_t)r * 32 + (lane >> 1)] = packed;
        float v1 = acc * asv, v2 = acc * adv;
        #pragma unroll
        for (int off = 32; off; off >>= 1) {
            v1 += __shfl_xor(v1, off, 64);
            v2 += __shfl_xor(v2, off, 64);
        }
        if (lane == 0) { ssrc[r] = v1; sdst[r] = v2; }
    }
}

// Pass 1 fused with layer-1 mm.
// Blocks [0,NBB): bin edges by dst>>6 into per-bin regions of `binned`,
//   entries packed 4B: src | dstLocal<<17 (src<2^17, dstLocal<64).
// Blocks [NBB, grid): layer-1 mm.
__global__ __launch_bounds__(256) void k_bin_mm1(const int* __restrict__ ei, int E,
        int* __restrict__ bin_ptr, unsigned* __restrict__ binned, int BCAP,
        const float* __restrict__ xin, const float* __restrict__ W,
        const float* __restrict__ a_src, const float* __restrict__ a_dst,
        unsigned* __restrict__ hb, float* __restrict__ ssrc, float* __restrict__ sdst, int N) {
    __shared__ int hist[NBINMAX], cur[NBINMAX];
    int tid = threadIdx.x, lane = tid & 63, wv = tid >> 6;
    if (blockIdx.x < NBB) {
        int nb = (N + NPB - 1) >> 6;
        for (int t = tid; t < nb; t += 256) hist[t] = 0;
        __syncthreads();
        int nq4 = E >> 2;
        int qpb = (nq4 + NBB - 1) / NBB;
        int q0 = blockIdx.x * qpb;
        int q1 = q0 + qpb; if (q1 > nq4) q1 = nq4;
        const int4* s4 = (const int4*)ei;
        const int4* d4 = (const int4*)(ei + E);
        // pass A: LDS histogram over bins (int atomics: native, fast)
        for (int i = q0 + tid; i < q1; i += 256) {
            int4 d = d4[i];
            atomicAdd(&hist[d.x >> 6], 1);
            atomicAdd(&hist[d.y >> 6], 1);
            atomicAdd(&hist[d.z >> 6], 1);
            atomicAdd(&hist[d.w >> 6], 1);
        }
        if (blockIdx.x == 0 && tid < (E & 3)) {
            int dd = ei[E + (nq4 << 2) + tid];
            atomicAdd(&hist[dd >> 6], 1);
        }
        __syncthreads();
        // reserve contiguous slices per bin (device atomics: one per (block,nonempty-bin))
        for (int t = tid; t < nb; t += 256)
            cur[t] = hist[t] ? atomicAdd(&bin_ptr[t], hist[t]) : 0;
        __syncthreads();
        // pass B: place packed edges (dst re-read is L2-hot)
        for (int i = q0 + tid; i < q1; i += 256) {
            int4 s = s4[i];
            int4 d = d4[i];
            int t0 = d.x >> 6, t1 = d.y >> 6, t2 = d.z >> 6, t3 = d.w >> 6;
            int p0 = atomicAdd(&cur[t0], 1);
            int p1 = atomicAdd(&cur[t1], 1);
            int p2 = atomicAdd(&cur[t2], 1);
            int p3 = atomicAdd(&cur[t3], 1);
            if (p0 < BCAP) binned[(size_t)t0 * BCAP + p0] = (unsigned)s.x | ((unsigned)(d.x & 63) << 17);
            if (p1 < BCAP) binned[(size_t)t1 * BCAP + p1] = (unsigned)s.y | ((unsigned)(d.y & 63) << 17);
            if (p2 < BCAP) binned[(size_t)t2 * BCAP + p2] = (unsigned)s.z | ((unsigned)(d.z & 63) << 17);
            if (p3 < BCAP) binned[(size_t)t3 * BCAP + p3] = (unsigned)s.w | ((unsigned)(d.w & 63) << 17);
        }
        if (blockIdx.x == 0 && tid < (E & 3)) {
            int i = (nq4 << 2) + tid;
            int ss = ei[i], dd = ei[E + i];
            int t = dd >> 6;
            int p = atomicAdd(&cur[t], 1);
            if (p < BCAP) binned[(size_t)t * BCAP + p] = (unsigned)ss | ((unsigned)(dd & 63) << 17);
        }
    } else {
        mm_rows(xin, W, a_src, a_dst, nullptr, nullptr, nullptr, nullptr, 0,
                hb, ssrc, sdst, N, blockIdx.x - NBB, gridDim.x - NBB, lane, wv);
    }
}

// standalone layer-2 mm (BN folded in)
__global__ __launch_bounds__(256) void k_mm_att(const float* __restrict__ xin,
        const float* __restrict__ W, const float* __restrict__ a_src, const float* __restrict__ a_dst,
        const float* __restrict__ bn_sum, const float* __restrict__ bn_sumsq,
        const float* __restrict__ gamma, const float* __restrict__ beta,
        unsigned* __restrict__ hb, float* __restrict__ ssrc, float* __restrict__ sdst, int N) {
    int tid = threadIdx.x, lane = tid & 63, wv = tid >> 6;
    mm_rows(xin, W, a_src, a_dst, bn_sum, bn_sumsq, gamma, beta, 1,
            hb, ssrc, sdst, N, blockIdx.x, gridDim.x, lane, wv);
}

// issue quad q of node's edge list into named register quad P
#define AGG_ISSUE(P, q) { \
    int sA_ = __shfl(sal0.x, (q), 16), sB_ = __shfl(sal0.y, (q), 16); \
    int sC_ = __shfl(sal0.z, (q), 16), sD_ = __shfl(sal0.w, (q), 16); \
    P##A = h2[(size_t)sA_ * 16 + sl]; P##B = h2[(size_t)sB_ * 16 + sl]; \
    P##C = h2[(size_t)sC_ * 16 + sl]; P##D = h2[(size_t)sD_ * 16 + sl]; }

// consume register quad P as quad index i
#define AGG_CONSUME(P, i) { \
    float eA_ = __shfl(e0, (i), 16), eB_ = __shfl(e1, (i), 16); \
    float eC_ = __shfl(e2, (i), 16), eD_ = __shfl(e3, (i), 16); \
    acc.x = fmaf(eA_, bflo(P##A.x), acc.x); acc.y = fmaf(eA_, bfhi(P##A.x), acc.y); \
    acc.z = fmaf(eA_, bflo(P##A.y), acc.z); acc.w = fmaf(eA_, bfhi(P##A.y), acc.w); \
    acc.x = fmaf(eB_, bflo(P##B.x), acc.x); acc.y = fmaf(eB_, bfhi(P##B.x), acc.y); \
    acc.z = fmaf(eB_, bflo(P##B.y), acc.z); acc.w = fmaf(eB_, bfhi(P##B.y), acc.w); \
    acc.x = fmaf(eC_, bflo(P##C.x), acc.x); acc.y = fmaf(eC_, bfhi(P##C.x), acc.y); \
    acc.z = fmaf(eC_, bflo(P##C.y), acc.z); acc.w = fmaf(eC_, bfhi(P##C.y), acc.w); \
    acc.x = fmaf(eD_, bflo(P##D.x), acc.x); acc.y = fmaf(eD_, bfhi(P##D.x), acc.y); \
    acc.z = fmaf(eD_, bflo(P##D.y), acc.z); acc.w = fmaf(eD_, bfhi(P##D.y), acc.w); }

// Aggregation with IN-LDS CSR: one block per 64-dst-node bin. The block
// streams its bin's packed edges (coalesced) and counting-sorts them into a
// 16KB LDS bucket array with NATIVE INT LDS atomics (k_scatter's proven-fast
// op — round-7's poison was FLOAT LDS RMW). This deletes k_scatter, the 25.6MB
// col array, and col's ~25MB contribution to agg FETCH, and lifts occupancy
// (1563 blocks, 17KB LDS, ~6/CU). Gather phase = round-10's 16-lane-subgroup
// depth-3 pipeline, with sal reads now from LDS (near-zero stage-A latency).
// mode 0: out = agg/z + bias (fp32), accumulate BN col sums.
// mode 1: out = 0.5*(x + agg/z + bias)
__global__ __launch_bounds__(256) void k_agg(const unsigned* __restrict__ binned,
        const int* __restrict__ bin_ptr, int BCAP,
        const float* __restrict__ ssrc, const float* __restrict__ sdst,
        const unsigned* __restrict__ hb, const float* __restrict__ bias,
        const float* __restrict__ x, float* __restrict__ out,
        float* __restrict__ bn_sum, float* __restrict__ bn_sumsq, int mode, int N) {
    __shared__ int colL[NPB][CAP];     // 16KB bucket CSR
    __shared__ int cntL[NPB];
    __shared__ float ssL[NPB], sdL[NPB];
    __shared__ float sbn1[D], sbn2[D];
    int tid = threadIdx.x;
    int sl = tid & 15;                 // lane within sub-group; covers cols 4sl..4sl+3
    int g = tid >> 4;                  // sub-group 0..15
    int b = blockIdx.x;
    int n0 = b << 6;

    if (tid < NPB) {
        cntL[tid] = 0;
        int nd = n0 + tid;
        ssL[tid] = (nd < N) ? ssrc[nd] : 0.f;
        sdL[tid] = (nd < N) ? sdst[nd] : 0.f;
    }
    if (mode == 0 && tid < D) { sbn1[tid] = 0.f; sbn2[tid] = 0.f; }
    __syncthreads();

    // build LDS CSR (int LDS atomics, native ds_add_rtn)
    int m = bin_ptr[b]; if (m > BCAP) m = BCAP;
    {
        const unsigned* base = binned + (size_t)b * BCAP;
        for (int i = tid; i < m; i += 256) {
            unsigned e = base[i];
            int dl = (int)(e >> 17);
            int k = atomicAdd(&cntL[dl], 1);
            if (k < CAP) colL[dl][k] = (int)(e & 0x1FFFFu);
        }
    }
    __syncthreads();

    const uint2* h2 = (const uint2*)hb;           // row = 16 uint2
    float4 s1 = make_float4(0, 0, 0, 0), s2 = make_float4(0, 0, 0, 0);

    // read node d's sal quad from LDS (clamped lanes -> valid node id)
    auto loadSal = [&](int d, int& dg, int4& sal) {
        int dgl = cntL[d]; if (dgl > CAP) dgl = CAP;
        int4 c = ((const int4*)colL[d])[sl];      // 16B-aligned, conflict-free
        int eb = sl << 2;
        int nd = n0 + d;
        int self = (nd < N) ? nd : 0;
        sal.x = (eb + 0 < dgl) ? c.x : self;
        sal.y = (eb + 1 < dgl) ? c.y : self;
        sal.z = (eb + 2 < dgl) ? c.z : self;
        sal.w = (eb + 3 < dgl) ? c.w : self;
        dg = dgl;
    };

    // sub-group g handles local nodes g, g+16, g+32, g+48
    int dg0; int4 sal0;
    loadSal(g, dg0, sal0);
    float4 g0;
    g0.x = ssrc[sal0.x]; g0.y = ssrc[sal0.y];
    g0.z = ssrc[sal0.z]; g0.w = ssrc[sal0.w];

    #pragma unroll
    for (int idx = 0; idx < 4; ++idx) {
        int d = g + (idx << 4);
        int nd = n0 + d;
        int ndc = (nd < N) ? nd : 0;
        // ---- issue current node's self row + quads 0..2 ----
        uint2 hv = h2[(size_t)ndc * 16 + sl];
        int Q = dg0 > 0 ? ((dg0 + 3) >> 2) : 1;
        uint2 p0A, p0B, p0C, p0D, p1A, p1B, p1C, p1D, p2A, p2B, p2C, p2D;
        AGG_ISSUE(p0, 0)
        if (Q > 1) AGG_ISSUE(p1, 1)
        if (Q > 2) AGG_ISSUE(p2, 2)

        // ---- prep next node: sal from LDS (instant) + issue its g-gathers ----
        int dg1 = 0; int4 sal1 = make_int4(0, 0, 0, 0);
        float4 g1 = make_float4(0, 0, 0, 0);
        if (idx < 3) {
            loadSal(d + 16, dg1, sal1);
            g1.x = ssrc[sal1.x]; g1.y = ssrc[sal1.y];
            g1.z = ssrc[sal1.z]; g1.w = ssrc[sal1.w];
        }

        // ---- e/z from g0 (gathers issued one node earlier) ----
        float sdn = sdL[d];
        int eb = sl << 2;
        float e0 = (eb + 0 < dg0) ? __expf(lrelu(g0.x + sdn, 0.2f)) : 0.f;
        float e1 = (eb + 1 < dg0) ? __expf(lrelu(g0.y + sdn, 0.2f)) : 0.f;
        float e2 = (eb + 2 < dg0) ? __expf(lrelu(g0.z + sdn, 0.2f)) : 0.f;
        float e3 = (eb + 3 < dg0) ? __expf(lrelu(g0.w + sdn, 0.2f)) : 0.f;
        float z = (e0 + e1) + (e2 + e3);
        #pragma unroll
        for (int off = 1; off <= 8; off <<= 1) z += __shfl_xor(z, off, 64);
        float es = __expf(lrelu(ssL[d] + sdn, 0.2f));
        z += es;
        float4 acc;
        acc.x = es * bflo(hv.x); acc.y = es * bfhi(hv.x);
        acc.z = es * bflo(hv.y); acc.w = es * bfhi(hv.y);

        // ---- depth-3 pipelined quad loop (rotating named quads) ----
        int i = 0;
        while (true) {
            AGG_CONSUME(p0, i)
            if (i + 3 < Q) AGG_ISSUE(p0, i + 3)
            if (++i >= Q) break;
            AGG_CONSUME(p1, i)
            if (i + 3 < Q) AGG_ISSUE(p1, i + 3)
            if (++i >= Q) break;
            AGG_CONSUME(p2, i)
            if (i + 3 < Q) AGG_ISSUE(p2, i + 3)
            if (++i >= Q) break;
        }

        // epilogue — no cross-lane reduce; all 16 lanes store
        if (nd < N) {
            float inv = 1.f / z;
            float4 b4 = ((const float4*)bias)[sl];
            float4 v;
            v.x = acc.x * inv + b4.x; v.y = acc.y * inv + b4.y;
            v.z = acc.z * inv + b4.z; v.w = acc.w * inv + b4.w;
            if (mode == 0) {
                ((float4*)out)[(size_t)nd * 16 + sl] = v;
                s1.x += v.x; s1.y += v.y; s1.z += v.z; s1.w += v.w;
                s2.x += v.x * v.x; s2.y += v.y * v.y;
                s2.z += v.z * v.z; s2.w += v.w * v.w;
            } else {
                float4 xv = ((const float4*)x)[(size_t)nd * 16 + sl];
                v.x = 0.5f * (xv.x + v.x); v.y = 0.5f * (xv.y + v.y);
                v.z = 0.5f * (xv.z + v.z); v.w = 0.5f * (xv.w + v.w);
                ((float4*)out)[(size_t)nd * 16 + sl] = v;
            }
        }
        // shift node pipeline
        dg0 = dg1; sal0 = sal1; g0 = g1;
    }
    if (mode == 0) {
        int c = sl * 4;       // block-level epilogue only: 16 ops/thread once per block
        atomicAdd(&sbn1[c + 0], s1.x); atomicAdd(&sbn1[c + 1], s1.y);
        atomicAdd(&sbn1[c + 2], s1.z); atomicAdd(&sbn1[c + 3], s1.w);
        atomicAdd(&sbn2[c + 0], s2.x); atomicAdd(&sbn2[c + 1], s2.y);
        atomicAdd(&sbn2[c + 2], s2.z); atomicAdd(&sbn2[c + 3], s2.w);
        __syncthreads();
        if (tid < D) {
            atomicAdd(&bn_sum[tid], sbn1[tid]);
            atomicAdd(&bn_sumsq[tid], sbn2[tid]);
        }
    }
}

extern "C" void kernel_launch(void* const* d_in, const int* in_sizes, int n_in,
                              void* d_out, int out_size, void* d_ws, size_t ws_size,
                              hipStream_t stream) {
    const float* x     = (const float*)d_in[0];
    const float* W1    = (const float*)d_in[1];
    const float* as1   = (const float*)d_in[2];
    const float* ad1   = (const float*)d_in[3];
    const float* b1    = (const float*)d_in[4];
    const float* gamma = (const float*)d_in[5];
    const float* beta  = (const float*)d_in[6];
    const float* W2    = (const float*)d_in[7];
    const float* as2   = (const float*)d_in[8];
    const float* ad2   = (const float*)d_in[9];
    const float* b2    = (const float*)d_in[10];
    const int*   ei    = (const int*)d_in[11];
    int N = in_sizes[0] / D;
    int E = in_sizes[11] / 2;
    float* out = (float*)d_out;          // layer-1 output buffer (fp32), then final

    float* ws = (float*)d_ws;
    unsigned* hb = (unsigned*)ws;                 // bf16-packed h: N*32 uints (12.8MB)
    float* ssrc = (float*)(hb + (size_t)N * 32);
    float* sdst = ssrc + N;
    int* binp   = (int*)(sdst + N);               // NBINMAX bin totals (memset)
    float* bn   = (float*)(binp + NBINMAX);       // 128: sum(64) | sumsq(64) (memset, contiguous)
    unsigned* binned = (unsigned*)(bn + 128);     // nb*BCAP packed edges (~9.6MB, in ws:
                                                  // must SURVIVE until agg2 — no d_out alias)

    int nb = (N + NPB - 1) >> 6;                  // 1563 bins for N=100K
    int BCAP = E / nb + (E / nb) / 4 + 256;       // avg + 25% + slack (~16 sigma)

    dim3 blk(256);

    // zero bin totals + bn in one async memset
    hipMemsetAsync(binp, 0, NBINMAX * 4 + 512, stream);

    // ---- pass 1: bin edges (packed 4B, 64-node bins) fused with layer-1 mm ----
    k_bin_mm1<<<2048, blk, 0, stream>>>(ei, E, binp, binned, BCAP,
                                        x, W1, as1, ad1, hb, ssrc, sdst, N);

    // ---- layer 1 aggregate (in-LDS CSR; k_scatter + col eliminated) ----
    k_agg<<<nb, blk, 0, stream>>>(binned, binp, BCAP, ssrc, sdst, hb, b1,
                                  nullptr, out, bn, bn + 64, 0, N);

    // ---- layer 2 (BN stats folded into mm preamble; final mix fused into agg) ----
    k_mm_att<<<2048, blk, 0, stream>>>(out, W2, as2, ad2, bn, bn + 64, gamma, beta,
                                       hb, ssrc, sdst, N);
    k_agg<<<nb, blk, 0, stream>>>(binned, binp, BCAP, ssrc, sdst, hb, b2,
                                  x, out, bn, bn + 64, 1, N);
}

// Round 12
// 246.115 us; speedup vs baseline: 6.3846x; 1.1623x over previous
//
#include <hip/hip_runtime.h>
#include <math.h>

#define D 64
#define CAP 64     // per-node bucket: 64 edges; P(deg>64)~5e-16 for Poisson(16)
#define NBB 128    // blocks doing the bin pass (rest of grid runs mm1)
#define NPB 64     // nodes per bin (dst >> 6); 1563 bins for N=100K
#define NBINMAX 2048

typedef __attribute__((ext_vector_type(8))) short bf16x8;
typedef __attribute__((ext_vector_type(4))) float f32x4;

__device__ __forceinline__ float lrelu(float x, float s) { return x > 0.f ? x : s * x; }

// f32 -> bf16 round-to-nearest-even
__device__ __forceinline__ unsigned f2bf(float f) {
    unsigned b = __builtin_bit_cast(unsigned, f);
    return (b + 0x7fffu + ((b >> 16) & 1u)) >> 16;
}
__device__ __forceinline__ float bflo(unsigned u) { return __builtin_bit_cast(float, u << 16); }
__device__ __forceinline__ float bfhi(unsigned u) { return __builtin_bit_cast(float, u & 0xffff0000u); }

// MFMA mm body (round-12): [N x 64] @ [64 x 64] on matrix cores.
// Old mm_rows: readlane+FMA, ~128 wave-ops/row for 64 useful FMAs (VALU-bound,
// ~50us/kernel). MFMA 16x16x32_bf16 layouts (cdna4_isa §10, m89-verified C/D):
//   A: row=lane&15, k=(lane>>4)*8+e   B: col=lane&15, k=(lane>>4)*8+e
//   C/D: col=lane&15, row=(lane>>4)*4+reg
// Each wave: 16-row tiles; W register-resident as 8 B-frags; per tile 2 A-frag
// loads (wave-coalesced: lanes {kg=0..3} cover each 256B x-row) + 8 MFMAs.
// ssrc/sdst from the fp32 accumulator (dot over jb cols + 16-lane shfl reduce).
__device__ __forceinline__ void mm_mfma(const float* __restrict__ xin,
        const float* __restrict__ W, const float* __restrict__ a_src, const float* __restrict__ a_dst,
        const float* __restrict__ bn_sum, const float* __restrict__ bn_sumsq,
        const float* __restrict__ gamma, const float* __restrict__ beta, int apply_bn,
        unsigned* __restrict__ hb, float* __restrict__ ssrc, float* __restrict__ sdst,
        int N, int wave, int nwaves, int lane) {
    int row16 = lane & 15;     // A-row within tile / C-col within jb block
    int kg = lane >> 4;        // k-group 0..3

    // B fragments: wf[kc][jb][e] = W[kc*32 + kg*8 + e][jb*16 + row16]
    bf16x8 wf[2][4];
    #pragma unroll
    for (int kc = 0; kc < 2; ++kc)
        #pragma unroll
        for (int jb = 0; jb < 4; ++jb) {
            bf16x8 f;
            #pragma unroll
            for (int e = 0; e < 8; ++e)
                f[e] = (short)f2bf(W[(kc * 32 + kg * 8 + e) * D + jb * 16 + row16]);
            wf[kc][jb] = f;
        }
    float asv[4], adv[4];
    #pragma unroll
    for (int jb = 0; jb < 4; ++jb) {
        asv[jb] = a_src[jb * 16 + row16];
        adv[jb] = a_dst[jb * 16 + row16];
    }
    // BN scale/shift for the 16 K-columns this lane loads
    float sc[2][8], sh[2][8];
    if (apply_bn) {
        #pragma unroll
        for (int kc = 0; kc < 2; ++kc)
            #pragma unroll
            for (int e = 0; e < 8; ++e) {
                int c = kc * 32 + kg * 8 + e;
                float mu = bn_sum[c] / (float)N;
                float var = bn_sumsq[c] / (float)N - mu * mu;   // biased var = jnp.var
                float rs = rsqrtf(var + 1e-5f);
                sc[kc][e] = rs * gamma[c];
                sh[kc][e] = beta[c] - mu * sc[kc][e];
            }
    }

    int ntiles = (N + 15) >> 4;
    for (int t = wave; t < ntiles; t += nwaves) {
        int r0 = t << 4;
        int arow = r0 + row16;
        int arowc = arow < N ? arow : N - 1;      // tail clamp (N%16==0: never taken)
        // A fragments: 8 consecutive fp32 per lane (two float4), BN+act, cvt bf16
        bf16x8 af[2];
        #pragma unroll
        for (int kc = 0; kc < 2; ++kc) {
            const float* p = xin + (size_t)arowc * D + kc * 32 + kg * 8;
            float4 u0 = *(const float4*)p;
            float4 u1 = *(const float4*)(p + 4);
            float v[8] = {u0.x, u0.y, u0.z, u0.w, u1.x, u1.y, u1.z, u1.w};
            bf16x8 f;
            #pragma unroll
            for (int e = 0; e < 8; ++e) {
                float vv = v[e];
                if (apply_bn) { vv = vv * sc[kc][e] + sh[kc][e]; vv = vv > 0.f ? vv : 0.01f * vv; }
                f[e] = (short)f2bf(vv);
            }
            af[kc] = f;
        }
        f32x4 acc0 = {0,0,0,0}, acc1 = {0,0,0,0}, acc2 = {0,0,0,0}, acc3 = {0,0,0,0};
        acc0 = __builtin_amdgcn_mfma_f32_16x16x32_bf16(af[0], wf[0][0], acc0, 0, 0, 0);
        acc1 = __builtin_amdgcn_mfma_f32_16x16x32_bf16(af[0], wf[0][1], acc1, 0, 0, 0);
        acc2 = __builtin_amdgcn_mfma_f32_16x16x32_bf16(af[0], wf[0][2], acc2, 0, 0, 0);
        acc3 = __builtin_amdgcn_mfma_f32_16x16x32_bf16(af[0], wf[0][3], acc3, 0, 0, 0);
        acc0 = __builtin_amdgcn_mfma_f32_16x16x32_bf16(af[1], wf[1][0], acc0, 0, 0, 0);
        acc1 = __builtin_amdgcn_mfma_f32_16x16x32_bf16(af[1], wf[1][1], acc1, 0, 0, 0);
        acc2 = __builtin_amdgcn_mfma_f32_16x16x32_bf16(af[1], wf[1][2], acc2, 0, 0, 0);
        acc3 = __builtin_amdgcn_mfma_f32_16x16x32_bf16(af[1], wf[1][3], acc3, 0, 0, 0);

        // epilogue: lane holds C rows kg*4+r (r=0..3), col jb*16+row16
        #pragma unroll
        for (int r = 0; r < 4; ++r) {
            int row = r0 + kg * 4 + r;
            float c0 = acc0[r], c1 = acc1[r], c2 = acc2[r], c3 = acc3[r];
            // hb pack: pair adjacent cols via shfl_xor(1); even row16 lanes store
            float p0 = __shfl_xor(c0, 1, 64);
            float p1 = __shfl_xor(c1, 1, 64);
            float p2 = __shfl_xor(c2, 1, 64);
            float p3 = __shfl_xor(c3, 1, 64);
            if (!(row16 & 1) && row < N) {
                size_t hbase = (size_t)row * 32 + (row16 >> 1);
                hb[hbase + 0]  = f2bf(c0) | (f2bf(p0) << 16);
                hb[hbase + 8]  = f2bf(c1) | (f2bf(p1) << 16);
                hb[hbase + 16] = f2bf(c2) | (f2bf(p2) << 16);
                hb[hbase + 24] = f2bf(c3) | (f2bf(p3) << 16);
            }
            // ssrc/sdst: per-lane partial over jb cols, reduce across the 16-lane col group
            float vs = fmaf(c0, asv[0], fmaf(c1, asv[1], fmaf(c2, asv[2], c3 * asv[3])));
            float vd = fmaf(c0, adv[0], fmaf(c1, adv[1], fmaf(c2, adv[2], c3 * adv[3])));
            #pragma unroll
            for (int off = 1; off <= 8; off <<= 1) {
                vs += __shfl_xor(vs, off, 64);
                vd += __shfl_xor(vd, off, 64);
            }
            if (row16 == 0 && row < N) { ssrc[row] = vs; sdst[row] = vd; }
        }
    }
}

// Pass 1 fused with layer-1 mm.
// Blocks [0,NBB): bin edges by dst>>6 into per-bin regions of `binned`,
//   entries packed 4B: src | dstLocal<<17 (src<2^17, dstLocal<64).
// Blocks [NBB, grid): layer-1 mm (MFMA).
__global__ __launch_bounds__(256) void k_bin_mm1(const int* __restrict__ ei, int E,
        int* __restrict__ bin_ptr, unsigned* __restrict__ binned, int BCAP,
        const float* __restrict__ xin, const float* __restrict__ W,
        const float* __restrict__ a_src, const float* __restrict__ a_dst,
        unsigned* __restrict__ hb, float* __restrict__ ssrc, float* __restrict__ sdst, int N) {
    __shared__ int hist[NBINMAX], cur[NBINMAX];
    int tid = threadIdx.x, lane = tid & 63, wv = tid >> 6;
    if (blockIdx.x < NBB) {
        int nb = (N + NPB - 1) >> 6;
        for (int t = tid; t < nb; t += 256) hist[t] = 0;
        __syncthreads();
        int nq4 = E >> 2;
        int qpb = (nq4 + NBB - 1) / NBB;
        int q0 = blockIdx.x * qpb;
        int q1 = q0 + qpb; if (q1 > nq4) q1 = nq4;
        const int4* s4 = (const int4*)ei;
        const int4* d4 = (const int4*)(ei + E);
        // pass A: LDS histogram over bins (int atomics: native, fast)
        for (int i = q0 + tid; i < q1; i += 256) {
            int4 d = d4[i];
            atomicAdd(&hist[d.x >> 6], 1);
            atomicAdd(&hist[d.y >> 6], 1);
            atomicAdd(&hist[d.z >> 6], 1);
            atomicAdd(&hist[d.w >> 6], 1);
        }
        if (blockIdx.x == 0 && tid < (E & 3)) {
            int dd = ei[E + (nq4 << 2) + tid];
            atomicAdd(&hist[dd >> 6], 1);
        }
        __syncthreads();
        // reserve contiguous slices per bin (device atomics: one per (block,nonempty-bin))
        for (int t = tid; t < nb; t += 256)
            cur[t] = hist[t] ? atomicAdd(&bin_ptr[t], hist[t]) : 0;
        __syncthreads();
        // pass B: place packed edges (dst re-read is L2-hot)
        for (int i = q0 + tid; i < q1; i += 256) {
            int4 s = s4[i];
            int4 d = d4[i];
            int t0 = d.x >> 6, t1 = d.y >> 6, t2 = d.z >> 6, t3 = d.w >> 6;
            int p0 = atomicAdd(&cur[t0], 1);
            int p1 = atomicAdd(&cur[t1], 1);
            int p2 = atomicAdd(&cur[t2], 1);
            int p3 = atomicAdd(&cur[t3], 1);
            if (p0 < BCAP) binned[(size_t)t0 * BCAP + p0] = (unsigned)s.x | ((unsigned)(d.x & 63) << 17);
            if (p1 < BCAP) binned[(size_t)t1 * BCAP + p1] = (unsigned)s.y | ((unsigned)(d.y & 63) << 17);
            if (p2 < BCAP) binned[(size_t)t2 * BCAP + p2] = (unsigned)s.z | ((unsigned)(d.z & 63) << 17);
            if (p3 < BCAP) binned[(size_t)t3 * BCAP + p3] = (unsigned)s.w | ((unsigned)(d.w & 63) << 17);
        }
        if (blockIdx.x == 0 && tid < (E & 3)) {
            int i = (nq4 << 2) + tid;
            int ss = ei[i], dd = ei[E + i];
            int t = dd >> 6;
            int p = atomicAdd(&cur[t], 1);
            if (p < BCAP) binned[(size_t)t * BCAP + p] = (unsigned)ss | ((unsigned)(dd & 63) << 17);
        }
    } else {
        int wave = (blockIdx.x - NBB) * 4 + wv;
        int nwaves = (gridDim.x - NBB) * 4;
        mm_mfma(xin, W, a_src, a_dst, nullptr, nullptr, nullptr, nullptr, 0,
                hb, ssrc, sdst, N, wave, nwaves, lane);
    }
}

// standalone layer-2 mm (MFMA, BN folded in)
__global__ __launch_bounds__(256) void k_mm_att(const float* __restrict__ xin,
        const float* __restrict__ W, const float* __restrict__ a_src, const float* __restrict__ a_dst,
        const float* __restrict__ bn_sum, const float* __restrict__ bn_sumsq,
        const float* __restrict__ gamma, const float* __restrict__ beta,
        unsigned* __restrict__ hb, float* __restrict__ ssrc, float* __restrict__ sdst, int N) {
    int tid = threadIdx.x, lane = tid & 63, wv = tid >> 6;
    mm_mfma(xin, W, a_src, a_dst, bn_sum, bn_sumsq, gamma, beta, 1,
            hb, ssrc, sdst, N, blockIdx.x * 4 + wv, gridDim.x * 4, lane);
}

// issue quad q of node's edge list into named register quad P
#define AGG_ISSUE(P, q) { \
    int sA_ = __shfl(sal0.x, (q), 16), sB_ = __shfl(sal0.y, (q), 16); \
    int sC_ = __shfl(sal0.z, (q), 16), sD_ = __shfl(sal0.w, (q), 16); \
    P##A = h2[(size_t)sA_ * 16 + sl]; P##B = h2[(size_t)sB_ * 16 + sl]; \
    P##C = h2[(size_t)sC_ * 16 + sl]; P##D = h2[(size_t)sD_ * 16 + sl]; }

// consume register quad P as quad index i
#define AGG_CONSUME(P, i) { \
    float eA_ = __shfl(e0, (i), 16), eB_ = __shfl(e1, (i), 16); \
    float eC_ = __shfl(e2, (i), 16), eD_ = __shfl(e3, (i), 16); \
    acc.x = fmaf(eA_, bflo(P##A.x), acc.x); acc.y = fmaf(eA_, bfhi(P##A.x), acc.y); \
    acc.z = fmaf(eA_, bflo(P##A.y), acc.z); acc.w = fmaf(eA_, bfhi(P##A.y), acc.w); \
    acc.x = fmaf(eB_, bflo(P##B.x), acc.x); acc.y = fmaf(eB_, bfhi(P##B.x), acc.y); \
    acc.z = fmaf(eB_, bflo(P##B.y), acc.z); acc.w = fmaf(eB_, bfhi(P##B.y), acc.w); \
    acc.x = fmaf(eC_, bflo(P##C.x), acc.x); acc.y = fmaf(eC_, bfhi(P##C.x), acc.y); \
    acc.z = fmaf(eC_, bflo(P##C.y), acc.z); acc.w = fmaf(eC_, bfhi(P##C.y), acc.w); \
    acc.x = fmaf(eD_, bflo(P##D.x), acc.x); acc.y = fmaf(eD_, bfhi(P##D.x), acc.y); \
    acc.z = fmaf(eD_, bflo(P##D.y), acc.z); acc.w = fmaf(eD_, bfhi(P##D.y), acc.w); }

// Aggregation with IN-LDS CSR (round-11 form, unchanged — confirmed at the
// random-gather service-rate wall; 68.6us/dispatch).
// mode 0: out = agg/z + bias (fp32), accumulate BN col sums.
// mode 1: out = 0.5*(x + agg/z + bias)
__global__ __launch_bounds__(256) void k_agg(const unsigned* __restrict__ binned,
        const int* __restrict__ bin_ptr, int BCAP,
        const float* __restrict__ ssrc, const float* __restrict__ sdst,
        const unsigned* __restrict__ hb, const float* __restrict__ bias,
        const float* __restrict__ x, float* __restrict__ out,
        float* __restrict__ bn_sum, float* __restrict__ bn_sumsq, int mode, int N) {
    __shared__ int colL[NPB][CAP];     // 16KB bucket CSR
    __shared__ int cntL[NPB];
    __shared__ float ssL[NPB], sdL[NPB];
    __shared__ float sbn1[D], sbn2[D];
    int tid = threadIdx.x;
    int sl = tid & 15;                 // lane within sub-group; covers cols 4sl..4sl+3
    int g = tid >> 4;                  // sub-group 0..15
    int b = blockIdx.x;
    int n0 = b << 6;

    if (tid < NPB) {
        cntL[tid] = 0;
        int nd = n0 + tid;
        ssL[tid] = (nd < N) ? ssrc[nd] : 0.f;
        sdL[tid] = (nd < N) ? sdst[nd] : 0.f;
    }
    if (mode == 0 && tid < D) { sbn1[tid] = 0.f; sbn2[tid] = 0.f; }
    __syncthreads();

    // build LDS CSR (int LDS atomics, native ds_add_rtn)
    int m = bin_ptr[b]; if (m > BCAP) m = BCAP;
    {
        const unsigned* base = binned + (size_t)b * BCAP;
        for (int i = tid; i < m; i += 256) {
            unsigned e = base[i];
            int dl = (int)(e >> 17);
            int k = atomicAdd(&cntL[dl], 1);
            if (k < CAP) colL[dl][k] = (int)(e & 0x1FFFFu);
        }
    }
    __syncthreads();

    const uint2* h2 = (const uint2*)hb;           // row = 16 uint2
    float4 s1 = make_float4(0, 0, 0, 0), s2 = make_float4(0, 0, 0, 0);

    // read node d's sal quad from LDS (clamped lanes -> valid node id)
    auto loadSal = [&](int d, int& dg, int4& sal) {
        int dgl = cntL[d]; if (dgl > CAP) dgl = CAP;
        int4 c = ((const int4*)colL[d])[sl];      // 16B-aligned, conflict-free
        int eb = sl << 2;
        int nd = n0 + d;
        int self = (nd < N) ? nd : 0;
        sal.x = (eb + 0 < dgl) ? c.x : self;
        sal.y = (eb + 1 < dgl) ? c.y : self;
        sal.z = (eb + 2 < dgl) ? c.z : self;
        sal.w = (eb + 3 < dgl) ? c.w : self;
        dg = dgl;
    };

    // sub-group g handles local nodes g, g+16, g+32, g+48
    int dg0; int4 sal0;
    loadSal(g, dg0, sal0);
    float4 g0;
    g0.x = ssrc[sal0.x]; g0.y = ssrc[sal0.y];
    g0.z = ssrc[sal0.z]; g0.w = ssrc[sal0.w];

    #pragma unroll
    for (int idx = 0; idx < 4; ++idx) {
        int d = g + (idx << 4);
        int nd = n0 + d;
        int ndc = (nd < N) ? nd : 0;
        // ---- issue current node's self row + quads 0..2 ----
        uint2 hv = h2[(size_t)ndc * 16 + sl];
        int Q = dg0 > 0 ? ((dg0 + 3) >> 2) : 1;
        uint2 p0A, p0B, p0C, p0D, p1A, p1B, p1C, p1D, p2A, p2B, p2C, p2D;
        AGG_ISSUE(p0, 0)
        if (Q > 1) AGG_ISSUE(p1, 1)
        if (Q > 2) AGG_ISSUE(p2, 2)

        // ---- prep next node: sal from LDS (instant) + issue its g-gathers ----
        int dg1 = 0; int4 sal1 = make_int4(0, 0, 0, 0);
        float4 g1 = make_float4(0, 0, 0, 0);
        if (idx < 3) {
            loadSal(d + 16, dg1, sal1);
            g1.x = ssrc[sal1.x]; g1.y = ssrc[sal1.y];
            g1.z = ssrc[sal1.z]; g1.w = ssrc[sal1.w];
        }

        // ---- e/z from g0 (gathers issued one node earlier) ----
        float sdn = sdL[d];
        int eb = sl << 2;
        float e0 = (eb + 0 < dg0) ? __expf(lrelu(g0.x + sdn, 0.2f)) : 0.f;
        float e1 = (eb + 1 < dg0) ? __expf(lrelu(g0.y + sdn, 0.2f)) : 0.f;
        float e2 = (eb + 2 < dg0) ? __expf(lrelu(g0.z + sdn, 0.2f)) : 0.f;
        float e3 = (eb + 3 < dg0) ? __expf(lrelu(g0.w + sdn, 0.2f)) : 0.f;
        float z = (e0 + e1) + (e2 + e3);
        #pragma unroll
        for (int off = 1; off <= 8; off <<= 1) z += __shfl_xor(z, off, 64);
        float es = __expf(lrelu(ssL[d] + sdn, 0.2f));
        z += es;
        float4 acc;
        acc.x = es * bflo(hv.x); acc.y = es * bfhi(hv.x);
        acc.z = es * bflo(hv.y); acc.w = es * bfhi(hv.y);

        // ---- depth-3 pipelined quad loop (rotating named quads) ----
        int i = 0;
        while (true) {
            AGG_CONSUME(p0, i)
            if (i + 3 < Q) AGG_ISSUE(p0, i + 3)
            if (++i >= Q) break;
            AGG_CONSUME(p1, i)
            if (i + 3 < Q) AGG_ISSUE(p1, i + 3)
            if (++i >= Q) break;
            AGG_CONSUME(p2, i)
            if (i + 3 < Q) AGG_ISSUE(p2, i + 3)
            if (++i >= Q) break;
        }

        // epilogue — no cross-lane reduce; all 16 lanes store
        if (nd < N) {
            float inv = 1.f / z;
            float4 b4 = ((const float4*)bias)[sl];
            float4 v;
            v.x = acc.x * inv + b4.x; v.y = acc.y * inv + b4.y;
            v.z = acc.z * inv + b4.z; v.w = acc.w * inv + b4.w;
            if (mode == 0) {
                ((float4*)out)[(size_t)nd * 16 + sl] = v;
                s1.x += v.x; s1.y += v.y; s1.z += v.z; s1.w += v.w;
                s2.x += v.x * v.x; s2.y += v.y * v.y;
                s2.z += v.z * v.z; s2.w += v.w * v.w;
            } else {
                float4 xv = ((const float4*)x)[(size_t)nd * 16 + sl];
                v.x = 0.5f * (xv.x + v.x); v.y = 0.5f * (xv.y + v.y);
                v.z = 0.5f * (xv.z + v.z); v.w = 0.5f * (xv.w + v.w);
                ((float4*)out)[(size_t)nd * 16 + sl] = v;
            }
        }
        // shift node pipeline
        dg0 = dg1; sal0 = sal1; g0 = g1;
    }
    if (mode == 0) {
        int c = sl * 4;       // block-level epilogue only: 16 ops/thread once per block
        atomicAdd(&sbn1[c + 0], s1.x); atomicAdd(&sbn1[c + 1], s1.y);
        atomicAdd(&sbn1[c + 2], s1.z); atomicAdd(&sbn1[c + 3], s1.w);
        atomicAdd(&sbn2[c + 0], s2.x); atomicAdd(&sbn2[c + 1], s2.y);
        atomicAdd(&sbn2[c + 2], s2.z); atomicAdd(&sbn2[c + 3], s2.w);
        __syncthreads();
        if (tid < D) {
            atomicAdd(&bn_sum[tid], sbn1[tid]);
            atomicAdd(&bn_sumsq[tid], sbn2[tid]);
        }
    }
}

extern "C" void kernel_launch(void* const* d_in, const int* in_sizes, int n_in,
                              void* d_out, int out_size, void* d_ws, size_t ws_size,
                              hipStream_t stream) {
    const float* x     = (const float*)d_in[0];
    const float* W1    = (const float*)d_in[1];
    const float* as1   = (const float*)d_in[2];
    const float* ad1   = (const float*)d_in[3];
    const float* b1    = (const float*)d_in[4];
    const float* gamma = (const float*)d_in[5];
    const float* beta  = (const float*)d_in[6];
    const float* W2    = (const float*)d_in[7];
    const float* as2   = (const float*)d_in[8];
    const float* ad2   = (const float*)d_in[9];
    const float* b2    = (const float*)d_in[10];
    const int*   ei    = (const int*)d_in[11];
    int N = in_sizes[0] / D;
    int E = in_sizes[11] / 2;
    float* out = (float*)d_out;          // layer-1 output buffer (fp32), then final

    float* ws = (float*)d_ws;
    unsigned* hb = (unsigned*)ws;                 // bf16-packed h: N*32 uints (12.8MB)
    float* ssrc = (float*)(hb + (size_t)N * 32);
    float* sdst = ssrc + N;
    int* binp   = (int*)(sdst + N);               // NBINMAX bin totals (memset)
    float* bn   = (float*)(binp + NBINMAX);       // 128: sum(64) | sumsq(64) (memset, contiguous)
    unsigned* binned = (unsigned*)(bn + 128);     // nb*BCAP packed edges (~9.6MB, in ws:
                                                  // must SURVIVE until agg2 — no d_out alias)

    int nb = (N + NPB - 1) >> 6;                  // 1563 bins for N=100K
    int BCAP = E / nb + (E / nb) / 4 + 256;       // avg + 25% + slack (~16 sigma)

    dim3 blk(256);

    // zero bin totals + bn in one async memset
    hipMemsetAsync(binp, 0, NBINMAX * 4 + 512, stream);

    // ---- pass 1: bin edges (packed 4B, 64-node bins) fused with layer-1 MFMA mm ----
    k_bin_mm1<<<2048, blk, 0, stream>>>(ei, E, binp, binned, BCAP,
                                        x, W1, as1, ad1, hb, ssrc, sdst, N);

    // ---- layer 1 aggregate (in-LDS CSR) ----
    k_agg<<<nb, blk, 0, stream>>>(binned, binp, BCAP, ssrc, sdst, hb, b1,
                                  nullptr, out, bn, bn + 64, 0, N);

    // ---- layer 2 (MFMA mm with BN folded; final mix fused into agg) ----
    k_mm_att<<<1024, blk, 0, stream>>>(out, W2, as2, ad2, bn, bn + 64, gamma, beta,
                                       hb, ssrc, sdst, N);
    k_agg<<<nb, blk, 0, stream>>>(binned, binp, BCAP, ssrc, sdst, hb, b2,
                                  x, out, bn, bn + 64, 1, N);
}